// Round 15
// baseline (180.518 us; speedup 1.0000x reference)
//
#include <hip/hip_runtime.h>
#include <hip/hip_bf16.h>
#include <math.h>

#define B_ 2
#define I_ 1024
#define C_ 16
#define H_ 12

__device__ __constant__ float kW_C = 0.23570226039551584f; // sqrt(2/(9*4))
#define W_Lc 0.5773502691896258f
#define LOG2E 1.4426950408889634f

typedef _Float16 hf;
typedef hf hf2 __attribute__((ext_vector_type(2)));
typedef hf hf4v __attribute__((ext_vector_type(4)));
typedef hf hf8v __attribute__((ext_vector_type(8)));
typedef float f32x4 __attribute__((ext_vector_type(4)));
typedef unsigned int u32;

template <typename T, typename F>
__device__ inline T bc(F f) { return __builtin_bit_cast(T, f); }

__device__ inline float fdot2f(u32 a, u32 b, float c) {
#if __has_builtin(__builtin_amdgcn_fdot2)
  return __builtin_amdgcn_fdot2(bc<hf2>(a), bc<hf2>(b), c, false);
#else
  hf2 x = bc<hf2>(a), y = bc<hf2>(b);
  return c + (float)x[0] * (float)y[0] + (float)x[1] * (float)y[1];
#endif
}

__device__ inline u32 pkrtz(float lo, float hi) {
#if __has_builtin(__builtin_amdgcn_cvt_pkrtz)
  return bc<u32>(__builtin_amdgcn_cvt_pkrtz(lo, hi));
#else
  hf2 t; t[0] = (hf)lo; t[1] = (hf)hi; return bc<u32>(t);
#endif
}

__device__ inline u32 permlo(u32 hiw, u32 low) { // (lo16=low.lo, hi16=hiw.lo)
#if __has_builtin(__builtin_amdgcn_perm)
  return __builtin_amdgcn_perm(hiw, low, 0x05040100u);
#else
  return (low & 0xffffu) | (hiw << 16);
#endif
}
__device__ inline u32 permhi(u32 hiw, u32 low) { // (lo16=low.hi, hi16=hiw.hi)
#if __has_builtin(__builtin_amdgcn_perm)
  return __builtin_amdgcn_perm(hiw, low, 0x07060302u);
#else
  return (low >> 16) | (hiw & 0xffff0000u);
#endif
}

// ws layout (float units):
// QF16 [B][I][392] hf   per-h 32 feats (q' | qp'' | cw*q2 | 1 | 0 0)
// KF16 [B][I][392] hf   per-h 32 feats (k | kp | 1 | cw*k2 | 0 0)
// VPP  [B][512 jp][12 h][48 us] paired vpts (ushort idx n*2+(j&1), n=p*3+x)
// VV   [B][I][192] f32
// SM   [B][12][1024][2] f32 (m, 1/S)
// pm   [B][64][64 icw][192] float2
// LT   [B][12][512 jp][1024 i] u32 slots = (l_j0, l_j1) f16 pair
// acc2 [B][I][jch][512] f16 (opts 0:288, opair 288:480, rowsum 480:492)
#define QF16_OFF 0
#define QF16_SZ (B_*I_*196)
#define KF16_OFF (QF16_OFF + QF16_SZ)
#define KF16_SZ QF16_SZ
#define VPF_OFF (KF16_OFF + KF16_SZ)
#define VPF_SZ (B_*I_*144)
#define VV_OFF (VPF_OFF + VPF_SZ)
#define VV_SZ (B_*I_*192)
#define SM_OFF (VV_OFF + VV_SZ)
#define SM_SZ (B_*12*1024*2)
#define PM_OFF (SM_OFF + SM_SZ)
#define PM_SZ (B_*64*64*192*2)
#define LT_OFF (PM_OFF + PM_SZ)
#define LT_SZ (B_*H_*512*1024)
#define ACC2_OFF (LT_OFF + LT_SZ)

__global__ __launch_bounds__(192) void kA(const float* __restrict__ s, const float* __restrict__ R,
                 const float* __restrict__ t, const float* __restrict__ Wq,
                 const float* __restrict__ Wk, const float* __restrict__ Wv,
                 const float* __restrict__ Wqp, const float* __restrict__ Wkp,
                 const float* __restrict__ Wvp, const float* __restrict__ gam,
                 float* __restrict__ ws) {
  int blk = blockIdx.x;
  int b = blk >> 10, i = blk & 1023;
  int tid = threadIdx.x;
  __shared__ float sl[16], rl[9], tl[3], part[96];
  if (tid < 16) sl[tid] = s[(b*I_ + i)*C_ + tid];
  else if (tid < 25) rl[tid-16] = R[(size_t)(b*I_+i)*9 + (tid-16)];
  else if (tid < 28) tl[tid-25] = t[(size_t)(b*I_+i)*3 + (tid-25)];
  __syncthreads();
  hf* QF  = (hf*)(ws + QF16_OFF) + (size_t)(b*I_+i)*392;
  hf* KF  = (hf*)(ws + KF16_OFF) + (size_t)(b*I_+i)*392;
  ushort* VPP = (ushort*)(ws + VPF_OFF);
  float* vv = ws + VV_OFF + (size_t)(b*I_+i)*192;
  {
    int hc = tid; int h = hc >> 4, c = hc & 15;
    float aq = 0.f, ak = 0.f, av = 0.f;
    #pragma unroll
    for (int ci = 0; ci < 16; ci++) {
      float sv = sl[ci];
      aq += sv * Wq[ci*192 + hc];
      ak += sv * Wk[ci*192 + hc];
      av += sv * Wv[ci*192 + hc];
    }
    const float s_qk = 0.25f * W_Lc * LOG2E;
    QF[h*32 + c] = (hf)(aq * s_qk);
    KF[h*32 + c] = (hf)ak;
    vv[hc] = av;
  }
  {
    float raw[3], px[3];
    if (tid < 96) {
      bool isq = tid < 48;
      int n = isq ? tid : tid - 48;
      const float* W = isq ? Wqp : Wkp;
      #pragma unroll
      for (int x = 0; x < 3; x++) {
        float a2 = 0.f;
        #pragma unroll
        for (int ci = 0; ci < 16; ci++) a2 += sl[ci] * W[ci*144 + n*3 + x];
        raw[x] = a2;
      }
      #pragma unroll
      for (int x = 0; x < 3; x++)
        px[x] = rl[x*3]*raw[0] + rl[x*3+1]*raw[1] + rl[x*3+2]*raw[2] + tl[x];
      int h = n >> 2, p = n & 3;
      part[tid] = px[0]*px[0] + px[1]*px[1] + px[2]*px[2];
      if (isq) {
        float g = gam[h];
        float sp = log1pf(expf(g));
        float coef2 = -0.5f * kW_C * sp * W_Lc * LOG2E;
        #pragma unroll
        for (int x = 0; x < 3; x++) QF[h*32 + 16 + p*3 + x] = (hf)(px[x] * (-2.0f * coef2));
      } else {
        #pragma unroll
        for (int x = 0; x < 3; x++) KF[h*32 + 16 + p*3 + x] = (hf)px[x];
      }
    } else {
      int n = tid - 96;
      #pragma unroll
      for (int x = 0; x < 3; x++) {
        float a2 = 0.f;
        #pragma unroll
        for (int ci = 0; ci < 16; ci++) a2 += sl[ci] * Wvp[ci*288 + n*3 + x];
        raw[x] = a2;
      }
      #pragma unroll
      for (int x = 0; x < 3; x++)
        px[x] = rl[x*3]*raw[0] + rl[x*3+1]*raw[1] + rl[x*3+2]*raw[2] + tl[x];
      int h = n >> 3, p = n & 7;
      size_t base = ((size_t)(b*512 + (i >> 1))*12 + h)*48 + (i & 1);
      #pragma unroll
      for (int x = 0; x < 3; x++) VPP[base + (p*3 + x)*2] = bc<ushort>((hf)px[x]);
    }
  }
  __syncthreads();
  if (tid < 24) {
    int h = tid % 12; bool isq = tid < 12;
    float g = gam[h];
    float sp = log1pf(expf(g));
    float coef2 = -0.5f * kW_C * sp * W_Lc * LOG2E;
    float s2 = 0.f;
    int base = isq ? h*4 : 48 + h*4;
    #pragma unroll
    for (int p = 0; p < 4; p++) s2 += part[base + p];
    if (isq) {
      QF[h*32 + 28] = (hf)(coef2 * s2);
      QF[h*32 + 29] = (hf)1.0f;
      QF[h*32 + 30] = (hf)0.0f;
      QF[h*32 + 31] = (hf)0.0f;
    } else {
      KF[h*32 + 28] = (hf)1.0f;
      KF[h*32 + 29] = (hf)(coef2 * s2);
      KF[h*32 + 30] = (hf)0.0f;
      KF[h*32 + 31] = (hf)0.0f;
    }
  }
}

// Pass 1 (MFMA, barrier-free, 2-wave blocks): block = (b, jt of 64, icb of 32).
// Each wave owns ONE 16i x 16j tile. z loads batched 8-deep; per-head QF/KF
// prefetched one head ahead; stats fully in-wave; per-tile (mx,es) -> pm direct.
__global__ __launch_bounds__(128,6) void kB(const float* __restrict__ z,
                 const float* __restrict__ Wb, float* __restrict__ ws) {
  int blk = blockIdx.x;
  int icb = blk & 31; int jt = (blk >> 5) & 63; int b = blk >> 11;
  int tid = threadIdx.x;
  int w = tid >> 6, lane = tid & 63;
  int ln15 = lane & 15, l16 = lane >> 4;
  int j0 = jt*16;
  int icw = icb*2 + w;
  int i0 = icw*16;
  __shared__ u32 lb[2*16*113];   // wave-private [16 i][113: slot h*9+jp]
  int wbase = w*(16*113);
  const ushort* QFu = (const ushort*)(ws + QF16_OFF);
  const ushort* KFu = (const ushort*)(ws + KF16_OFF);
  // Wb B-frag for bias MFMA: B[k=c][n=h]; lane: h=ln15, c=l16*4+e
  hf4v wbf;
  #pragma unroll
  for (int e = 0; e < 4; e++) {
    int c = l16*4 + e;
    float v = (ln15 < 12) ? Wb[c*12 + ln15] * (W_Lc*LOG2E) : 0.f;
    wbf[e] = (hf)v;
  }
  u32* LTu_w = (u32*)(ws + LT_OFF);
  // bias phase: two batches of 8 independent z loads, then 8 MFMAs each
  #pragma unroll
  for (int bat = 0; bat < 2; ++bat) {
    float4 zr0, zr1, zr2, zr3, zr4, zr5, zr6, zr7;
    {
      const float* zb = z + ((size_t)(b*I_ + i0 + bat*8)*I_ + j0 + ln15)*16 + l16*4;
      const size_t rs = (size_t)I_*16;
      zr0 = *(const float4*)(zb);
      zr1 = *(const float4*)(zb + rs);
      zr2 = *(const float4*)(zb + rs*2);
      zr3 = *(const float4*)(zb + rs*3);
      zr4 = *(const float4*)(zb + rs*4);
      zr5 = *(const float4*)(zb + rs*5);
      zr6 = *(const float4*)(zb + rs*6);
      zr7 = *(const float4*)(zb + rs*7);
    }
    #pragma unroll
    for (int u = 0; u < 8; ++u) {
      float4 zv = (u==0)?zr0:(u==1)?zr1:(u==2)?zr2:(u==3)?zr3:(u==4)?zr4:(u==5)?zr5:(u==6)?zr6:zr7;
      int ii = bat*8 + u;
      uint2 ap = make_uint2(pkrtz(zv.x, zv.y), pkrtz(zv.z, zv.w));
      hf4v a = bc<hf4v>(ap);
      f32x4 cb = {0.f, 0.f, 0.f, 0.f};
      cb = __builtin_amdgcn_mfma_f32_16x16x16f16(a, wbf, cb, 0, 0, 0);
      if (ln15 < 12) {
        lb[wbase + ii*113 + ln15*9 + l16*2]     = pkrtz(cb[0], cb[1]);
        lb[wbase + ii*113 + ln15*9 + l16*2 + 1] = pkrtz(cb[2], cb[3]);
      }
    }
  }
  // head loop: QK MFMA + bias add + stats + LT pack; prefetch next head's frags
  float2* pm = (float2*)(ws + PM_OFF) + ((size_t)((b*64 + jt)*64 + icw))*192;
  const size_t qfb = (size_t)(b*I_ + i0 + ln15)*392 + l16*8;
  const size_t kfb = (size_t)(b*I_ + j0 + ln15)*392 + l16*8;
  hf8v aqn = *(const hf8v*)&QFu[qfb];
  hf8v bkn = *(const hf8v*)&KFu[kfb];
  #pragma unroll
  for (int h = 0; h < 12; ++h) {
    hf8v aq = aqn, bk = bkn;
    if (h < 11) {
      aqn = *(const hf8v*)&QFu[qfb + (h+1)*32];
      bkn = *(const hf8v*)&KFu[kfb + (h+1)*32];
    }
    f32x4 c = {0.f, 0.f, 0.f, 0.f};
    c = __builtin_amdgcn_mfma_f32_16x16x32_f16(aq, bk, c, 0, 0, 0);
    // lane holds C: i = i0 + l16*4 + reg, j = ln15
    int ib = wbase + (l16*4)*113 + h*9 + (ln15 >> 1);
    int par = (ln15 & 1) << 4;
    float l0 = c[0] + (float)bc<hf>((ushort)(lb[ib]       >> par));
    float l1 = c[1] + (float)bc<hf>((ushort)(lb[ib + 113] >> par));
    float l2 = c[2] + (float)bc<hf>((ushort)(lb[ib + 226] >> par));
    float l3 = c[3] + (float)bc<hf>((ushort)(lb[ib + 339] >> par));
    hf h0 = (hf)l0, h1 = (hf)l1, h2 = (hf)l2, h3 = (hf)l3;
    float r0 = (float)h0, r1 = (float)h1, r2 = (float)h2, r3 = (float)h3;
    float mx = fmaxf(fmaxf(r0, r1), fmaxf(r2, r3));
    mx = fmaxf(mx, __shfl_xor(mx, 16));
    mx = fmaxf(mx, __shfl_xor(mx, 32));
    float es = __builtin_amdgcn_exp2f(r0 - mx) + __builtin_amdgcn_exp2f(r1 - mx)
             + __builtin_amdgcn_exp2f(r2 - mx) + __builtin_amdgcn_exp2f(r3 - mx);
    es += __shfl_xor(es, 16);
    es += __shfl_xor(es, 32);
    // pack (l_j0, l_j1) per i and store coalesced
    u32 me01 = (u32)bc<ushort>(h0) | ((u32)bc<ushort>(h1) << 16);
    u32 me23 = (u32)bc<ushort>(h2) | ((u32)bc<ushort>(h3) << 16);
    u32 p01 = (u32)__shfl_xor((int)me01, 1);
    u32 p23 = (u32)__shfl_xor((int)me23, 1);
    if ((ln15 & 1) == 0) {
      u32 w0 = permlo(p01, me01), w1 = permhi(p01, me01);
      u32 w2 = permlo(p23, me23), w3 = permhi(p23, me23);
      u32* dst = LTu_w + ((size_t)(b*12 + h)*512 + jt*8 + (ln15 >> 1))*1024 + i0 + l16*4;
      *(uint4*)dst = make_uint4(w0, w1, w2, w3);
    }
    if (l16 == 0) pm[h*16 + ln15] = make_float2(mx, es);
  }
}

// merge 64 partial (m,S) -> SM[b][h][j] = (m, 1/S)
__global__ __launch_bounds__(192) void kB2(float* __restrict__ ws) {
  int blk = blockIdx.x; int jt = blk & 63, b = blk >> 6;
  int tid = threadIdx.x; int h = tid >> 4, jl = tid & 15;
  const float2* pm = (const float2*)(ws + PM_OFF) + (size_t)(b*64+jt)*64*192 + tid;
  float m = -1e30f, S = 0.f;
  #pragma unroll 4
  for (int ic = 0; ic < 64; ic++) {
    float2 p = pm[ic*192];
    float mn = fmaxf(m, p.x);
    S = S * __builtin_amdgcn_exp2f(m - mn) + p.y * __builtin_amdgcn_exp2f(p.x - mn);
    m = mn;
  }
  int j = jt*16 + jl;
  float* sm = ws + SM_OFF + ((size_t)((b*12+h)*1024) + j)*2;
  sm[0] = m;
  sm[1] = 1.0f / S;
}

// Pass 2: block = (b, it of 64, jc of jch). 16 i, stream I_/jch j. thr=(h,il).
// No QK/bias: weights come from LT; z staged PAIRED; vpp/sm direct from L2.
__global__ __launch_bounds__(192,6) void kC(const float* __restrict__ z,
                 float* __restrict__ ws, int jsh) {
  int blk = blockIdx.x;
  int jch = 1 << jsh;
  int jc = blk & (jch-1); int it = (blk >> jsh) & 63; int b = blk >> (jsh+6);
  int tid = threadIdx.x; int h = tid >> 4, il = tid & 15;
  int i = it*16 + il;
  __shared__ u32 llds[96*18];     // [h*8+jp][16 i-pairs, stride 18]
  __shared__ u32 zplds[16*132];   // [i][jp*16 + c] paired (z_j0[c], z_j1[c])
  float opts[24], opair[16], rsum = 0.f;
  #pragma unroll
  for (int n = 0; n < 24; n++) opts[n] = 0.f;
  #pragma unroll
  for (int c = 0; c < 16; c++) opair[c] = 0.f;
  const u32* LTu = (const u32*)(ws + LT_OFF);
  const float* SM = ws + SM_OFF + (size_t)((b*12+h)*1024)*2;
  const ushort* VPP = (const ushort*)(ws + VPF_OFF);
  int chunk = I_ >> jsh;
  int nt = chunk >> 4;
  int hh = tid >> 4, rr = tid & 15, sjp = rr >> 1, sq = rr & 1;  // llds staging roles
  for (int t = 0; t < nt; ++t) {
    int j0 = jc*chunk + t*16;
    int jpg0 = j0 >> 1;
    __syncthreads();
    {
      const u32* src = LTu + ((size_t)(b*12+hh)*512 + jpg0 + sjp)*1024 + it*16 + sq*8;
      uint4 a = *(const uint4*)src;
      uint4 c4 = *(const uint4*)(src + 4);
      u32* drow = llds + (hh*8 + sjp)*18 + sq*8;
      *(uint2*)(drow + 0) = make_uint2(a.x, a.y);
      *(uint2*)(drow + 2) = make_uint2(a.z, a.w);
      *(uint2*)(drow + 4) = make_uint2(c4.x, c4.y);
      *(uint2*)(drow + 6) = make_uint2(c4.z, c4.w);
    }
    for (int idx = tid; idx < 512; idx += 192) {
      int r = idx >> 5, jp = (idx >> 2) & 7, c4 = idx & 3;
      const float* zb = z + ((size_t)(b*I_ + it*16 + r)*I_ + j0 + 2*jp)*16 + c4*4;
      float4 a = *(const float4*)zb;
      float4 d = *(const float4*)(zb + 16);
      uint4 o = make_uint4(pkrtz(a.x, d.x), pkrtz(a.y, d.y), pkrtz(a.z, d.z), pkrtz(a.w, d.w));
      *(uint4*)&zplds[r*132 + jp*16 + c4*4] = o;
    }
    __syncthreads();
    #pragma unroll 1
    for (int jp = 0; jp < 8; ++jp) {
      u32 lp = llds[(h*8 + jp)*18 + il];
      float4 st = *(const float4*)(SM + (size_t)(j0 + 2*jp)*2);
      const uint4* vp4 = (const uint4*)(VPP + ((size_t)(b*512 + jpg0 + jp)*12 + h)*48);
      uint4 va = vp4[0], vb = vp4[1], vc = vp4[2];
      uint4 vd = vp4[3], ve = vp4[4], vf = vp4[5];
      hf2 lh = bc<hf2>(lp);
      float w0 = __builtin_amdgcn_exp2f((float)lh[0] - st.x) * st.y;
      float w1 = __builtin_amdgcn_exp2f((float)lh[1] - st.z) * st.w;
      rsum += w0 + w1;
      u32 w2 = pkrtz(w0, w1);
      const u32* zr = &zplds[il*132 + jp*16];
      uint4 p0 = *(const uint4*)(zr + 0), p1 = *(const uint4*)(zr + 4);
      uint4 p2 = *(const uint4*)(zr + 8), p3 = *(const uint4*)(zr + 12);
      opair[0]  = fdot2f(w2, p0.x, opair[0]);
      opair[1]  = fdot2f(w2, p0.y, opair[1]);
      opair[2]  = fdot2f(w2, p0.z, opair[2]);
      opair[3]  = fdot2f(w2, p0.w, opair[3]);
      opair[4]  = fdot2f(w2, p1.x, opair[4]);
      opair[5]  = fdot2f(w2, p1.y, opair[5]);
      opair[6]  = fdot2f(w2, p1.z, opair[6]);
      opair[7]  = fdot2f(w2, p1.w, opair[7]);
      opair[8]  = fdot2f(w2, p2.x, opair[8]);
      opair[9]  = fdot2f(w2, p2.y, opair[9]);
      opair[10] = fdot2f(w2, p2.z, opair[10]);
      opair[11] = fdot2f(w2, p2.w, opair[11]);
      opair[12] = fdot2f(w2, p3.x, opair[12]);
      opair[13] = fdot2f(w2, p3.y, opair[13]);
      opair[14] = fdot2f(w2, p3.z, opair[14]);
      opair[15] = fdot2f(w2, p3.w, opair[15]);
      opts[0]  = fdot2f(w2, va.x, opts[0]);
      opts[1]  = fdot2f(w2, va.y, opts[1]);
      opts[2]  = fdot2f(w2, va.z, opts[2]);
      opts[3]  = fdot2f(w2, va.w, opts[3]);
      opts[4]  = fdot2f(w2, vb.x, opts[4]);
      opts[5]  = fdot2f(w2, vb.y, opts[5]);
      opts[6]  = fdot2f(w2, vb.z, opts[6]);
      opts[7]  = fdot2f(w2, vb.w, opts[7]);
      opts[8]  = fdot2f(w2, vc.x, opts[8]);
      opts[9]  = fdot2f(w2, vc.y, opts[9]);
      opts[10] = fdot2f(w2, vc.z, opts[10]);
      opts[11] = fdot2f(w2, vc.w, opts[11]);
      opts[12] = fdot2f(w2, vd.x, opts[12]);
      opts[13] = fdot2f(w2, vd.y, opts[13]);
      opts[14] = fdot2f(w2, vd.z, opts[14]);
      opts[15] = fdot2f(w2, vd.w, opts[15]);
      opts[16] = fdot2f(w2, ve.x, opts[16]);
      opts[17] = fdot2f(w2, ve.y, opts[17]);
      opts[18] = fdot2f(w2, ve.z, opts[18]);
      opts[19] = fdot2f(w2, ve.w, opts[19]);
      opts[20] = fdot2f(w2, vf.x, opts[20]);
      opts[21] = fdot2f(w2, vf.y, opts[21]);
      opts[22] = fdot2f(w2, vf.z, opts[22]);
      opts[23] = fdot2f(w2, vf.w, opts[23]);
    }
  }
  ushort* ab = (ushort*)(ws + ACC2_OFF) + ((size_t)(b*I_+i)*jch + jc)*512;
  #pragma unroll
  for (int n = 0; n < 24; n++) ab[h*24 + n] = bc<ushort>((hf)opts[n]);
  #pragma unroll
  for (int c = 0; c < 16; c++) ab[288 + h*16 + c] = bc<ushort>((hf)opair[c]);
  ab[480 + h] = bc<ushort>((hf)rsum);
}

// Epilogue: reduce jch f16 partials, build cat[4][768], out = cat @ Wout + bout.
__global__ __launch_bounds__(256) void kD(const float* __restrict__ Wout, const float* __restrict__ bout,
                 const float* __restrict__ ws, float* __restrict__ out, int jsh) {
  int jch = 1 << jsh;
  int blk = blockIdx.x;
  int b = blk >> 8; int i0 = (blk & 255) << 2;
  int tid = threadIdx.x;
  __shared__ float accs[4*512];
  __shared__ float cat[4*776];
  __shared__ float red[256];
  const ushort* ACC2us = (const ushort*)(ws + ACC2_OFF);
  for (int idx = tid; idx < 4*512; idx += 256) {
    int r = idx >> 9, f = idx & 511;
    const ushort* src = ACC2us + (size_t)(b*I_+i0+r)*jch*512 + f;
    float ssum = 0.f;
    for (int jc = 0; jc < jch; jc++) ssum += (float)bc<hf>(src[jc*512]);
    accs[idx] = ssum;
  }
  __syncthreads();
  const float* vv = ws + VV_OFF;
  for (int idx = tid; idx < 4*768; idx += 256) {
    int r = idx / 768, f = idx - r*768;
    int i = i0 + r;
    const float* ab = accs + r*512;
    float val;
    if (f < 192) {
      int h = f >> 4, c = f & 15;
      val = vv[(size_t)(b*I_+i)*192 + h*16 + c] * ab[480 + h];
    } else if (f < 384) {
      val = ab[288 + (f - 192)];
    } else if (f < 672) {
      val = ab[f - 384];
    } else {
      int g = f - 672; int base = (g >> 3)*24 + (g & 7)*3;
      float x0 = ab[base], x1 = ab[base+1], x2 = ab[base+2];
      val = sqrtf(fmaxf(x0*x0 + x1*x1 + x2*x2, 1e-12f));
    }
    cat[r*776 + f] = val;
  }
  __syncthreads();
  {
    int r = tid >> 6, c = (tid >> 2) & 15, sseg = tid & 3;
    const float* cr = cat + r*776;
    float a = 0.f;
    for (int f = sseg*192; f < sseg*192 + 192; f++) a += cr[f] * Wout[f*16 + c];
    red[tid] = a;
  }
  __syncthreads();
  if ((tid & 3) == 0) {
    int r = tid >> 6, c = (tid >> 2) & 15;
    float sum = bout[c] + red[tid] + red[tid+1] + red[tid+2] + red[tid+3];
    out[((size_t)(b*I_) + i0 + r)*16 + c] = sum;
  }
}

extern "C" void kernel_launch(void* const* d_in, const int* in_sizes, int n_in,
                              void* d_out, int out_size, void* d_ws, size_t ws_size,
                              hipStream_t stream) {
  const float* s    = (const float*)d_in[0];
  const float* z    = (const float*)d_in[1];
  const float* R    = (const float*)d_in[2];
  const float* t    = (const float*)d_in[3];
  const float* Wq   = (const float*)d_in[4];
  const float* Wk   = (const float*)d_in[5];
  const float* Wv   = (const float*)d_in[6];
  const float* Wb   = (const float*)d_in[7];
  const float* Wqp  = (const float*)d_in[8];
  const float* Wkp  = (const float*)d_in[9];
  const float* Wvp  = (const float*)d_in[10];
  const float* gam  = (const float*)d_in[11];
  const float* Wout = (const float*)d_in[12];
  const float* bout = (const float*)d_in[13];
  float* out = (float*)d_out;
  float* ws = (float*)d_ws;

  // pick largest jch (power of 2, <=16) whose f16 partial buffer fits ws
  int jsh = 4;
  while (jsh > 0) {
    size_t need = ((size_t)ACC2_OFF + (size_t)B_*I_*(1u<<jsh)*256) * 4u;
    if (need <= ws_size) break;
    jsh--;
  }

  hipLaunchKernelGGL(kA, dim3(B_*I_), dim3(192), 0, stream,
                     s, R, t, Wq, Wk, Wv, Wqp, Wkp, Wvp, gam, ws);
  hipLaunchKernelGGL(kB, dim3(B_*64*32), dim3(128), 0, stream, z, Wb, ws);
  hipLaunchKernelGGL(kB2, dim3(B_*64), dim3(192), 0, stream, ws);
  hipLaunchKernelGGL(kC, dim3(B_*64*(1<<jsh)), dim3(192), 0, stream, z, ws, jsh);
  hipLaunchKernelGGL(kD, dim3(B_*256), dim3(256), 0, stream, Wout, bout, ws, out, jsh);
}

// Round 16
// 179.978 us; speedup vs baseline: 1.0030x; 1.0030x over previous
//
#include <hip/hip_runtime.h>
#include <hip/hip_bf16.h>
#include <math.h>

#define B_ 2
#define I_ 1024
#define C_ 16
#define H_ 12
#define ICH 16

__device__ __constant__ float kW_C = 0.23570226039551584f; // sqrt(2/(9*4))
#define W_Lc 0.5773502691896258f
#define LOG2E 1.4426950408889634f

typedef _Float16 hf;
typedef hf hf2 __attribute__((ext_vector_type(2)));
typedef hf hf4v __attribute__((ext_vector_type(4)));
typedef hf hf8v __attribute__((ext_vector_type(8)));
typedef float f32x4 __attribute__((ext_vector_type(4)));
typedef unsigned int u32;

template <typename T, typename F>
__device__ inline T bc(F f) { return __builtin_bit_cast(T, f); }

__device__ inline float fdot2f(u32 a, u32 b, float c) {
#if __has_builtin(__builtin_amdgcn_fdot2)
  return __builtin_amdgcn_fdot2(bc<hf2>(a), bc<hf2>(b), c, false);
#else
  hf2 x = bc<hf2>(a), y = bc<hf2>(b);
  return c + (float)x[0] * (float)y[0] + (float)x[1] * (float)y[1];
#endif
}

__device__ inline u32 pkrtz(float lo, float hi) {
#if __has_builtin(__builtin_amdgcn_cvt_pkrtz)
  return bc<u32>(__builtin_amdgcn_cvt_pkrtz(lo, hi));
#else
  hf2 t; t[0] = (hf)lo; t[1] = (hf)hi; return bc<u32>(t);
#endif
}

__device__ inline u32 permlo(u32 hiw, u32 low) { // (lo16=low.lo, hi16=hiw.lo)
#if __has_builtin(__builtin_amdgcn_perm)
  return __builtin_amdgcn_perm(hiw, low, 0x05040100u);
#else
  return (low & 0xffffu) | (hiw << 16);
#endif
}
__device__ inline u32 permhi(u32 hiw, u32 low) { // (lo16=low.hi, hi16=hiw.hi)
#if __has_builtin(__builtin_amdgcn_perm)
  return __builtin_amdgcn_perm(hiw, low, 0x07060302u);
#else
  return (low >> 16) | (hiw & 0xffff0000u);
#endif
}

// ws layout (float units):
// QF16 [B][I][392] hf   per-h 32 feats (q' | qp'' | cw*q2 | 1 | 0 0)
// KF16 [B][I][392] hf   per-h 32 feats (k | kp | 1 | cw*k2 | 0 0)
// VPP  [B][512 jp][12 h][48 us] paired vpts (ushort idx n*2+(j&1), n=p*3+x)
// VV   [B][I][192] f32
// SM   [B][12][1024][2] f32 (m, 1/S)
// pm   [B][64][ICH][192] float2
// LT   [B][12][512 jp][1024 i] u32 slots = (l_j0, l_j1) f16 pair
// acc2 [B][I][jch][512] f16 (opts 0:288, opair 288:480, rowsum 480:492)
#define QF16_OFF 0
#define QF16_SZ (B_*I_*196)
#define KF16_OFF (QF16_OFF + QF16_SZ)
#define KF16_SZ QF16_SZ
#define VPF_OFF (KF16_OFF + KF16_SZ)
#define VPF_SZ (B_*I_*144)
#define VV_OFF (VPF_OFF + VPF_SZ)
#define VV_SZ (B_*I_*192)
#define SM_OFF (VV_OFF + VV_SZ)
#define SM_SZ (B_*12*1024*2)
#define PM_OFF (SM_OFF + SM_SZ)
#define PM_SZ (B_*64*ICH*192*2)
#define LT_OFF (PM_OFF + PM_SZ)
#define LT_SZ (B_*H_*512*1024)
#define ACC2_OFF (LT_OFF + LT_SZ)

__global__ __launch_bounds__(192) void kA(const float* __restrict__ s, const float* __restrict__ R,
                 const float* __restrict__ t, const float* __restrict__ Wq,
                 const float* __restrict__ Wk, const float* __restrict__ Wv,
                 const float* __restrict__ Wqp, const float* __restrict__ Wkp,
                 const float* __restrict__ Wvp, const float* __restrict__ gam,
                 float* __restrict__ ws) {
  int blk = blockIdx.x;
  int b = blk >> 10, i = blk & 1023;
  int tid = threadIdx.x;
  __shared__ float sl[16], rl[9], tl[3], part[96];
  if (tid < 16) sl[tid] = s[(b*I_ + i)*C_ + tid];
  else if (tid < 25) rl[tid-16] = R[(size_t)(b*I_+i)*9 + (tid-16)];
  else if (tid < 28) tl[tid-25] = t[(size_t)(b*I_+i)*3 + (tid-25)];
  __syncthreads();
  hf* QF  = (hf*)(ws + QF16_OFF) + (size_t)(b*I_+i)*392;
  hf* KF  = (hf*)(ws + KF16_OFF) + (size_t)(b*I_+i)*392;
  ushort* VPP = (ushort*)(ws + VPF_OFF);
  float* vv = ws + VV_OFF + (size_t)(b*I_+i)*192;
  {
    int hc = tid; int h = hc >> 4, c = hc & 15;
    float aq = 0.f, ak = 0.f, av = 0.f;
    #pragma unroll
    for (int ci = 0; ci < 16; ci++) {
      float sv = sl[ci];
      aq += sv * Wq[ci*192 + hc];
      ak += sv * Wk[ci*192 + hc];
      av += sv * Wv[ci*192 + hc];
    }
    const float s_qk = 0.25f * W_Lc * LOG2E;
    QF[h*32 + c] = (hf)(aq * s_qk);
    KF[h*32 + c] = (hf)ak;
    vv[hc] = av;
  }
  {
    float raw[3], px[3];
    if (tid < 96) {
      bool isq = tid < 48;
      int n = isq ? tid : tid - 48;
      const float* W = isq ? Wqp : Wkp;
      #pragma unroll
      for (int x = 0; x < 3; x++) {
        float a2 = 0.f;
        #pragma unroll
        for (int ci = 0; ci < 16; ci++) a2 += sl[ci] * W[ci*144 + n*3 + x];
        raw[x] = a2;
      }
      #pragma unroll
      for (int x = 0; x < 3; x++)
        px[x] = rl[x*3]*raw[0] + rl[x*3+1]*raw[1] + rl[x*3+2]*raw[2] + tl[x];
      int h = n >> 2, p = n & 3;
      part[tid] = px[0]*px[0] + px[1]*px[1] + px[2]*px[2];
      if (isq) {
        float g = gam[h];
        float sp = log1pf(expf(g));
        float coef2 = -0.5f * kW_C * sp * W_Lc * LOG2E;
        #pragma unroll
        for (int x = 0; x < 3; x++) QF[h*32 + 16 + p*3 + x] = (hf)(px[x] * (-2.0f * coef2));
      } else {
        #pragma unroll
        for (int x = 0; x < 3; x++) KF[h*32 + 16 + p*3 + x] = (hf)px[x];
      }
    } else {
      int n = tid - 96;
      #pragma unroll
      for (int x = 0; x < 3; x++) {
        float a2 = 0.f;
        #pragma unroll
        for (int ci = 0; ci < 16; ci++) a2 += sl[ci] * Wvp[ci*288 + n*3 + x];
        raw[x] = a2;
      }
      #pragma unroll
      for (int x = 0; x < 3; x++)
        px[x] = rl[x*3]*raw[0] + rl[x*3+1]*raw[1] + rl[x*3+2]*raw[2] + tl[x];
      int h = n >> 3, p = n & 7;
      size_t base = ((size_t)(b*512 + (i >> 1))*12 + h)*48 + (i & 1);
      #pragma unroll
      for (int x = 0; x < 3; x++) VPP[base + (p*3 + x)*2] = bc<ushort>((hf)px[x]);
    }
  }
  __syncthreads();
  if (tid < 24) {
    int h = tid % 12; bool isq = tid < 12;
    float g = gam[h];
    float sp = log1pf(expf(g));
    float coef2 = -0.5f * kW_C * sp * W_Lc * LOG2E;
    float s2 = 0.f;
    int base = isq ? h*4 : 48 + h*4;
    #pragma unroll
    for (int p = 0; p < 4; p++) s2 += part[base + p];
    if (isq) {
      QF[h*32 + 28] = (hf)(coef2 * s2);
      QF[h*32 + 29] = (hf)1.0f;
      QF[h*32 + 30] = (hf)0.0f;
      QF[h*32 + 31] = (hf)0.0f;
    } else {
      KF[h*32 + 28] = (hf)1.0f;
      KF[h*32 + 29] = (hf)(coef2 * s2);
      KF[h*32 + 30] = (hf)0.0f;
      KF[h*32 + 31] = (hf)0.0f;
    }
  }
}

// Pass 1 (MFMA, pipelined, LDS-slim): block = (b, jt of 64, ic of 16), 256 thr = 4 waves.
// 16 j x 64 i (4 tiles). QF A-frags direct from L2 (no qlds); z prefetched one tile
// ahead; lbias packed u32; in-reg LT pack (2x shfl_xor); 2 barriers/tile.
// (256,6): VGPR cap 85 vs ~55 used -> no spill; LDS 20.5 KB -> 6 blocks/CU.
__global__ __launch_bounds__(256,6) void kB(const float* __restrict__ z,
                 const float* __restrict__ Wb, float* __restrict__ ws) {
  int blk = blockIdx.x;
  int ic = blk & (ICH-1); int jt = (blk >> 4) & 63; int b = blk >> 10;
  int tid = threadIdx.x;
  int w = tid >> 6, lane = tid & 63;
  int ln15 = lane & 15, l16 = lane >> 4;
  int j0 = jt*16;
  __shared__ u32 lqk[12*16*18];      // 13824 B  [h][j][i(16)+pad2] f32 bits
  __shared__ u32 lbias32[16*112];    // 7168 B   [i][h*9 + jp]
  const ushort* QFu = (const ushort*)(ws + QF16_OFF);
  const ushort* KFu = (const ushort*)(ws + KF16_OFF);
  // K B-frags (j fixed for whole block): head h = w*3+q
  hf8v kf[3];
  #pragma unroll
  for (int q = 0; q < 3; q++) {
    int h = w*3 + q;
    kf[q] = *(const hf8v*)&KFu[(size_t)(b*I_ + j0 + ln15)*392 + h*32 + l16*8];
  }
  // Wb B-frag for bias MFMA: B[k=c][n=h]: lane: h=ln15, c=l16*4+e
  hf4v wbf;
  #pragma unroll
  for (int e = 0; e < 4; e++) {
    int c = l16*4 + e;
    float v = (ln15 < 12) ? Wb[c*12 + ln15] * (W_Lc*LOG2E) : 0.f;
    wbf[e] = (hf)v;
  }
  u32* LTu_w = (u32*)(ws + LT_OFF);
  float m = -1e30f, S = 0.f;
  // z prefetch for tile 0 (per wave: rows w*4..w*4+3)
  float4 zb0, zb1, zb2, zb3;
  {
    const float* zbase = z + ((size_t)(b*I_ + ic*64 + w*4)*I_ + j0 + ln15)*16 + l16*4;
    zb0 = *(const float4*)(zbase);
    zb1 = *(const float4*)(zbase + (size_t)I_*16);
    zb2 = *(const float4*)(zbase + (size_t)I_*32);
    zb3 = *(const float4*)(zbase + (size_t)I_*48);
  }
  for (int t = 0; t < 4; ++t) {
    int i0 = ic*64 + t*16;
    // QK MFMAs: head h = w*3+q; A-frag direct from global (L2-hot QF)
    #pragma unroll
    for (int q = 0; q < 3; q++) {
      int h = w*3 + q;
      hf8v a = *(const hf8v*)&QFu[(size_t)(b*I_ + i0 + ln15)*392 + h*32 + l16*8];
      f32x4 c = {0.f, 0.f, 0.f, 0.f};
      c = __builtin_amdgcn_mfma_f32_16x16x32_f16(a, kf[q], c, 0, 0, 0);
      u32* dst = &lqk[(h*16 + ln15)*18 + l16*4];
      *(uint2*)dst     = make_uint2(bc<u32>(c[0]), bc<u32>(c[1]));
      *(uint2*)(dst+2) = make_uint2(bc<u32>(c[2]), bc<u32>(c[3]));
    }
    // Bias MFMAs from prefetched z; C: h=ln15, j=l16*4+reg
    #pragma unroll
    for (int r = 0; r < 4; r++) {
      float4 zv = (r == 0) ? zb0 : (r == 1) ? zb1 : (r == 2) ? zb2 : zb3;
      int ii = w*4 + r;
      uint2 ap = make_uint2(pkrtz(zv.x, zv.y), pkrtz(zv.z, zv.w));
      hf4v a = bc<hf4v>(ap);
      f32x4 cb = {0.f, 0.f, 0.f, 0.f};
      cb = __builtin_amdgcn_mfma_f32_16x16x16f16(a, wbf, cb, 0, 0, 0);
      if (ln15 < 12) {
        u32 b01 = pkrtz(cb[0], cb[1]);
        u32 b23 = pkrtz(cb[2], cb[3]);
        *(uint2*)&lbias32[ii*112 + ln15*9 + l16*2] = make_uint2(b01, b23);
      }
    }
    // prefetch z for next tile (drains under stats)
    if (t < 3) {
      const float* zbase = z + ((size_t)(b*I_ + ic*64 + (t+1)*16 + w*4)*I_ + j0 + ln15)*16 + l16*4;
      zb0 = *(const float4*)(zbase);
      zb1 = *(const float4*)(zbase + (size_t)I_*16);
      zb2 = *(const float4*)(zbase + (size_t)I_*32);
      zb3 = *(const float4*)(zbase + (size_t)I_*48);
    }
    __syncthreads();
    // stats + in-register pack + LT write (threads < 192): thread=(h,jl)
    if (tid < 192) {
      int h = tid >> 4, jl = tid & 15;
      const u32* qk = &lqk[(h*16 + jl)*18];
      float l[16];
      #pragma unroll
      for (int i = 0; i < 16; i++) {
        u32 bb = lbias32[i*112 + h*9 + (jl >> 1)];
        ushort bu = (jl & 1) ? (ushort)(bb >> 16) : (ushort)(bb & 0xffffu);
        l[i] = bc<float>(qk[i]) + (float)bc<hf>(bu);
      }
      u32 lw[8];
      #pragma unroll
      for (int p = 0; p < 8; p++) lw[p] = pkrtz(l[2*p], l[2*p+1]);
      float lr[16];
      #pragma unroll
      for (int p = 0; p < 8; p++) { hf2 lh = bc<hf2>(lw[p]); lr[2*p] = (float)lh[0]; lr[2*p+1] = (float)lh[1]; }
      float m8[8];
      #pragma unroll
      for (int p = 0; p < 8; p++) m8[p] = fmaxf(lr[2*p], lr[2*p+1]);
      float mt = fmaxf(fmaxf(fmaxf(m8[0],m8[1]), fmaxf(m8[2],m8[3])),
                       fmaxf(fmaxf(m8[4],m8[5]), fmaxf(m8[6],m8[7])));
      float e[16];
      #pragma unroll
      for (int p = 0; p < 16; p++) e[p] = __builtin_amdgcn_exp2f(lr[p] - mt);
      float st = ((e[0]+e[1])+(e[2]+e[3])) + ((e[4]+e[5])+(e[6]+e[7]))
               + ((e[8]+e[9])+(e[10]+e[11])) + ((e[12]+e[13])+(e[14]+e[15]));
      float mn = fmaxf(m, mt);
      S = S * __builtin_amdgcn_exp2f(m - mn) + st * __builtin_amdgcn_exp2f(mt - mn);
      m = mn;
      // exchange 1: i-pairs -> j-pair LT words
      u32 ex[8];
      #pragma unroll
      for (int p = 0; p < 8; p++) {
        u32 pw = (u32)__shfl_xor((int)lw[p], 1);
        ex[p] = (jl & 1) ? permhi(lw[p], pw) : permlo(pw, lw[p]);
      }
      // exchange 2: interleave so each thread owns 8 consecutive i's of one row
      u32 sw[8];
      #pragma unroll
      for (int p = 0; p < 8; p++) sw[p] = (u32)__shfl_xor((int)ex[p], 1);
      int par = jl & 1;
      u32 o0 = par ? sw[4] : ex[0];
      u32 o1 = par ? ex[4] : sw[0];
      u32 o2 = par ? sw[5] : ex[1];
      u32 o3 = par ? ex[5] : sw[1];
      u32 o4 = par ? sw[6] : ex[2];
      u32 o5 = par ? ex[6] : sw[2];
      u32 o6 = par ? sw[7] : ex[3];
      u32 o7 = par ? ex[7] : sw[3];
      u32* dst = LTu_w + ((size_t)(b*12+h)*512 + jt*8 + (jl>>1))*1024 + i0 + par*8;
      *(uint4*)dst     = make_uint4(o0, o1, o2, o3);
      *(uint4*)(dst+4) = make_uint4(o4, o5, o6, o7);
    }
    __syncthreads();   // protect lqk/lbias32 before next tile's MFMA writes
  }
  if (tid < 192) {
    float2* pm = (float2*)(ws + PM_OFF);
    pm[((size_t)(b*64+jt)*ICH + ic)*192 + tid] = make_float2(m, S);
  }
}

// merge ICH partial (m,S) -> SM[b][h][j] = (m, 1/S)
__global__ __launch_bounds__(192) void kB2(float* __restrict__ ws) {
  int blk = blockIdx.x; int jt = blk & 63, b = blk >> 6;
  int tid = threadIdx.x; int h = tid >> 4, jl = tid & 15;
  const float2* pm = (const float2*)(ws + PM_OFF) + (size_t)(b*64+jt)*ICH*192 + tid;
  float m = -1e30f, S = 0.f;
  #pragma unroll
  for (int ic = 0; ic < ICH; ic++) {
    float2 p = pm[ic*192];
    float mn = fmaxf(m, p.x);
    S = S * __builtin_amdgcn_exp2f(m - mn) + p.y * __builtin_amdgcn_exp2f(p.x - mn);
    m = mn;
  }
  int j = jt*16 + jl;
  float* sm = ws + SM_OFF + ((size_t)((b*12+h)*1024) + j)*2;
  sm[0] = m;
  sm[1] = 1.0f / S;
}

// Pass 2: block = (b, it of 64, jc of jch). 16 i, stream I_/jch j. thr=(h,il).
// No QK/bias: weights come from LT; z staged PAIRED; vpp/sm direct from L2.
__global__ __launch_bounds__(192,6) void kC(const float* __restrict__ z,
                 float* __restrict__ ws, int jsh) {
  int blk = blockIdx.x;
  int jch = 1 << jsh;
  int jc = blk & (jch-1); int it = (blk >> jsh) & 63; int b = blk >> (jsh+6);
  int tid = threadIdx.x; int h = tid >> 4, il = tid & 15;
  int i = it*16 + il;
  __shared__ u32 llds[96*18];     // [h*8+jp][16 i-pairs, stride 18]
  __shared__ u32 zplds[16*132];   // [i][jp*16 + c] paired (z_j0[c], z_j1[c])
  float opts[24], opair[16], rsum = 0.f;
  #pragma unroll
  for (int n = 0; n < 24; n++) opts[n] = 0.f;
  #pragma unroll
  for (int c = 0; c < 16; c++) opair[c] = 0.f;
  const u32* LTu = (const u32*)(ws + LT_OFF);
  const float* SM = ws + SM_OFF + (size_t)((b*12+h)*1024)*2;
  const ushort* VPP = (const ushort*)(ws + VPF_OFF);
  int chunk = I_ >> jsh;
  int nt = chunk >> 4;
  int hh = tid >> 4, rr = tid & 15, sjp = rr >> 1, sq = rr & 1;  // llds staging roles
  for (int t = 0; t < nt; ++t) {
    int j0 = jc*chunk + t*16;
    int jpg0 = j0 >> 1;
    __syncthreads();
    {
      const u32* src = LTu + ((size_t)(b*12+hh)*512 + jpg0 + sjp)*1024 + it*16 + sq*8;
      uint4 a = *(const uint4*)src;
      uint4 c4 = *(const uint4*)(src + 4);
      u32* drow = llds + (hh*8 + sjp)*18 + sq*8;
      *(uint2*)(drow + 0) = make_uint2(a.x, a.y);
      *(uint2*)(drow + 2) = make_uint2(a.z, a.w);
      *(uint2*)(drow + 4) = make_uint2(c4.x, c4.y);
      *(uint2*)(drow + 6) = make_uint2(c4.z, c4.w);
    }
    for (int idx = tid; idx < 512; idx += 192) {
      int r = idx >> 5, jp = (idx >> 2) & 7, c4 = idx & 3;
      const float* zb = z + ((size_t)(b*I_ + it*16 + r)*I_ + j0 + 2*jp)*16 + c4*4;
      float4 a = *(const float4*)zb;
      float4 d = *(const float4*)(zb + 16);
      uint4 o = make_uint4(pkrtz(a.x, d.x), pkrtz(a.y, d.y), pkrtz(a.z, d.z), pkrtz(a.w, d.w));
      *(uint4*)&zplds[r*132 + jp*16 + c4*4] = o;
    }
    __syncthreads();
    #pragma unroll 1
    for (int jp = 0; jp < 8; ++jp) {
      u32 lp = llds[(h*8 + jp)*18 + il];
      float4 st = *(const float4*)(SM + (size_t)(j0 + 2*jp)*2);
      const uint4* vp4 = (const uint4*)(VPP + ((size_t)(b*512 + jpg0 + jp)*12 + h)*48);
      uint4 va = vp4[0], vb = vp4[1], vc = vp4[2];
      uint4 vd = vp4[3], ve = vp4[4], vf = vp4[5];
      hf2 lh = bc<hf2>(lp);
      float w0 = __builtin_amdgcn_exp2f((float)lh[0] - st.x) * st.y;
      float w1 = __builtin_amdgcn_exp2f((float)lh[1] - st.z) * st.w;
      rsum += w0 + w1;
      u32 w2 = pkrtz(w0, w1);
      const u32* zr = &zplds[il*132 + jp*16];
      uint4 p0 = *(const uint4*)(zr + 0), p1 = *(const uint4*)(zr + 4);
      uint4 p2 = *(const uint4*)(zr + 8), p3 = *(const uint4*)(zr + 12);
      opair[0]  = fdot2f(w2, p0.x, opair[0]);
      opair[1]  = fdot2f(w2, p0.y, opair[1]);
      opair[2]  = fdot2f(w2, p0.z, opair[2]);
      opair[3]  = fdot2f(w2, p0.w, opair[3]);
      opair[4]  = fdot2f(w2, p1.x, opair[4]);
      opair[5]  = fdot2f(w2, p1.y, opair[5]);
      opair[6]  = fdot2f(w2, p1.z, opair[6]);
      opair[7]  = fdot2f(w2, p1.w, opair[7]);
      opair[8]  = fdot2f(w2, p2.x, opair[8]);
      opair[9]  = fdot2f(w2, p2.y, opair[9]);
      opair[10] = fdot2f(w2, p2.z, opair[10]);
      opair[11] = fdot2f(w2, p2.w, opair[11]);
      opair[12] = fdot2f(w2, p3.x, opair[12]);
      opair[13] = fdot2f(w2, p3.y, opair[13]);
      opair[14] = fdot2f(w2, p3.z, opair[14]);
      opair[15] = fdot2f(w2, p3.w, opair[15]);
      opts[0]  = fdot2f(w2, va.x, opts[0]);
      opts[1]  = fdot2f(w2, va.y, opts[1]);
      opts[2]  = fdot2f(w2, va.z, opts[2]);
      opts[3]  = fdot2f(w2, va.w, opts[3]);
      opts[4]  = fdot2f(w2, vb.x, opts[4]);
      opts[5]  = fdot2f(w2, vb.y, opts[5]);
      opts[6]  = fdot2f(w2, vb.z, opts[6]);
      opts[7]  = fdot2f(w2, vb.w, opts[7]);
      opts[8]  = fdot2f(w2, vc.x, opts[8]);
      opts[9]  = fdot2f(w2, vc.y, opts[9]);
      opts[10] = fdot2f(w2, vc.z, opts[10]);
      opts[11] = fdot2f(w2, vc.w, opts[11]);
      opts[12] = fdot2f(w2, vd.x, opts[12]);
      opts[13] = fdot2f(w2, vd.y, opts[13]);
      opts[14] = fdot2f(w2, vd.z, opts[14]);
      opts[15] = fdot2f(w2, vd.w, opts[15]);
      opts[16] = fdot2f(w2, ve.x, opts[16]);
      opts[17] = fdot2f(w2, ve.y, opts[17]);
      opts[18] = fdot2f(w2, ve.z, opts[18]);
      opts[19] = fdot2f(w2, ve.w, opts[19]);
      opts[20] = fdot2f(w2, vf.x, opts[20]);
      opts[21] = fdot2f(w2, vf.y, opts[21]);
      opts[22] = fdot2f(w2, vf.z, opts[22]);
      opts[23] = fdot2f(w2, vf.w, opts[23]);
    }
  }
  ushort* ab = (ushort*)(ws + ACC2_OFF) + ((size_t)(b*I_+i)*jch + jc)*512;
  #pragma unroll
  for (int n = 0; n < 24; n++) ab[h*24 + n] = bc<ushort>((hf)opts[n]);
  #pragma unroll
  for (int c = 0; c < 16; c++) ab[288 + h*16 + c] = bc<ushort>((hf)opair[c]);
  ab[480 + h] = bc<ushort>((hf)rsum);
}

// Epilogue: reduce jch f16 partials, build cat[4][768], out = cat @ Wout + bout.
__global__ __launch_bounds__(256) void kD(const float* __restrict__ Wout, const float* __restrict__ bout,
                 const float* __restrict__ ws, float* __restrict__ out, int jsh) {
  int jch = 1 << jsh;
  int blk = blockIdx.x;
  int b = blk >> 8; int i0 = (blk & 255) << 2;
  int tid = threadIdx.x;
  __shared__ float accs[4*512];
  __shared__ float cat[4*776];
  __shared__ float red[256];
  const ushort* ACC2us = (const ushort*)(ws + ACC2_OFF);
  for (int idx = tid; idx < 4*512; idx += 256) {
    int r = idx >> 9, f = idx & 511;
    const ushort* src = ACC2us + (size_t)(b*I_+i0+r)*jch*512 + f;
    float ssum = 0.f;
    for (int jc = 0; jc < jch; jc++) ssum += (float)bc<hf>(src[jc*512]);
    accs[idx] = ssum;
  }
  __syncthreads();
  const float* vv = ws + VV_OFF;
  for (int idx = tid; idx < 4*768; idx += 256) {
    int r = idx / 768, f = idx - r*768;
    int i = i0 + r;
    const float* ab = accs + r*512;
    float val;
    if (f < 192) {
      int h = f >> 4, c = f & 15;
      val = vv[(size_t)(b*I_+i)*192 + h*16 + c] * ab[480 + h];
    } else if (f < 384) {
      val = ab[288 + (f - 192)];
    } else if (f < 672) {
      val = ab[f - 384];
    } else {
      int g = f - 672; int base = (g >> 3)*24 + (g & 7)*3;
      float x0 = ab[base], x1 = ab[base+1], x2 = ab[base+2];
      val = sqrtf(fmaxf(x0*x0 + x1*x1 + x2*x2, 1e-12f));
    }
    cat[r*776 + f] = val;
  }
  __syncthreads();
  {
    int r = tid >> 6, c = (tid >> 2) & 15, sseg = tid & 3;
    const float* cr = cat + r*776;
    float a = 0.f;
    for (int f = sseg*192; f < sseg*192 + 192; f++) a += cr[f] * Wout[f*16 + c];
    red[tid] = a;
  }
  __syncthreads();
  if ((tid & 3) == 0) {
    int r = tid >> 6, c = (tid >> 2) & 15;
    float sum = bout[c] + red[tid] + red[tid+1] + red[tid+2] + red[tid+3];
    out[((size_t)(b*I_) + i0 + r)*16 + c] = sum;
  }
}

extern "C" void kernel_launch(void* const* d_in, const int* in_sizes, int n_in,
                              void* d_out, int out_size, void* d_ws, size_t ws_size,
                              hipStream_t stream) {
  const float* s    = (const float*)d_in[0];
  const float* z    = (const float*)d_in[1];
  const float* R    = (const float*)d_in[2];
  const float* t    = (const float*)d_in[3];
  const float* Wq   = (const float*)d_in[4];
  const float* Wk   = (const float*)d_in[5];
  const float* Wv   = (const float*)d_in[6];
  const float* Wb   = (const float*)d_in[7];
  const float* Wqp  = (const float*)d_in[8];
  const float* Wkp  = (const float*)d_in[9];
  const float* Wvp  = (const float*)d_in[10];
  const float* gam  = (const float*)d_in[11];
  const float* Wout = (const float*)d_in[12];
  const float* bout = (const float*)d_in[13];
  float* out = (float*)d_out;
  float* ws = (float*)d_ws;

  // pick largest jch (power of 2, <=16) whose f16 partial buffer fits ws
  int jsh = 4;
  while (jsh > 0) {
    size_t need = ((size_t)ACC2_OFF + (size_t)B_*I_*(1u<<jsh)*256) * 4u;
    if (need <= ws_size) break;
    jsh--;
  }

  hipLaunchKernelGGL(kA, dim3(B_*I_), dim3(192), 0, stream,
                     s, R, t, Wq, Wk, Wv, Wqp, Wkp, Wvp, gam, ws);
  hipLaunchKernelGGL(kB, dim3(B_*64*ICH), dim3(256), 0, stream, z, Wb, ws);
  hipLaunchKernelGGL(kB2, dim3(B_*64), dim3(192), 0, stream, ws);
  hipLaunchKernelGGL(kC, dim3(B_*64*(1<<jsh)), dim3(192), 0, stream, z, ws, jsh);
  hipLaunchKernelGGL(kD, dim3(B_*256), dim3(256), 0, stream, Wout, bout, ws, out, jsh);
}

// Round 17
// 171.646 us; speedup vs baseline: 1.0517x; 1.0485x over previous
//
#include <hip/hip_runtime.h>
#include <hip/hip_bf16.h>
#include <math.h>

#define B_ 2
#define I_ 1024
#define C_ 16
#define H_ 12
#define ICH 16

__device__ __constant__ float kW_C = 0.23570226039551584f; // sqrt(2/(9*4))
#define W_Lc 0.5773502691896258f
#define LOG2E 1.4426950408889634f

typedef _Float16 hf;
typedef hf hf2 __attribute__((ext_vector_type(2)));
typedef hf hf4v __attribute__((ext_vector_type(4)));
typedef hf hf8v __attribute__((ext_vector_type(8)));
typedef float f32x4 __attribute__((ext_vector_type(4)));
typedef unsigned int u32;

template <typename T, typename F>
__device__ inline T bc(F f) { return __builtin_bit_cast(T, f); }

__device__ inline float fdot2f(u32 a, u32 b, float c) {
#if __has_builtin(__builtin_amdgcn_fdot2)
  return __builtin_amdgcn_fdot2(bc<hf2>(a), bc<hf2>(b), c, false);
#else
  hf2 x = bc<hf2>(a), y = bc<hf2>(b);
  return c + (float)x[0] * (float)y[0] + (float)x[1] * (float)y[1];
#endif
}

__device__ inline u32 pkrtz(float lo, float hi) {
#if __has_builtin(__builtin_amdgcn_cvt_pkrtz)
  return bc<u32>(__builtin_amdgcn_cvt_pkrtz(lo, hi));
#else
  hf2 t; t[0] = (hf)lo; t[1] = (hf)hi; return bc<u32>(t);
#endif
}

__device__ inline u32 permlo(u32 hiw, u32 low) { // (lo16=low.lo, hi16=hiw.lo)
#if __has_builtin(__builtin_amdgcn_perm)
  return __builtin_amdgcn_perm(hiw, low, 0x05040100u);
#else
  return (low & 0xffffu) | (hiw << 16);
#endif
}
__device__ inline u32 permhi(u32 hiw, u32 low) { // (lo16=low.hi, hi16=hiw.hi)
#if __has_builtin(__builtin_amdgcn_perm)
  return __builtin_amdgcn_perm(hiw, low, 0x07060302u);
#else
  return (low >> 16) | (hiw & 0xffff0000u);
#endif
}

// ws layout (float units):
// QF16 [B][I][392] hf   per-h 32 feats (q' | qp'' | cw*q2 | 1 | 0 0)
// KF16 [B][I][392] hf   per-h 32 feats (k | kp | 1 | cw*k2 | 0 0)
// VPP  [B][512 jp][12 h][48 us] paired vpts (ushort idx n*2+(j&1), n=p*3+x)
// VV   [B][I][192] f32
// SM   [B][12][1024][2] f32 (m, 1/S)
// pm   [B][64][ICH][192] float2
// LT   [B][12][512 jp][1024 i] u32 slots = (l_j0, l_j1) f16 pair
// acc2 [B][I][jch][512] f16 (opts 0:288, opair 288:480, rowsum 480:492)
#define QF16_OFF 0
#define QF16_SZ (B_*I_*196)
#define KF16_OFF (QF16_OFF + QF16_SZ)
#define KF16_SZ QF16_SZ
#define VPF_OFF (KF16_OFF + KF16_SZ)
#define VPF_SZ (B_*I_*144)
#define VV_OFF (VPF_OFF + VPF_SZ)
#define VV_SZ (B_*I_*192)
#define SM_OFF (VV_OFF + VV_SZ)
#define SM_SZ (B_*12*1024*2)
#define PM_OFF (SM_OFF + SM_SZ)
#define PM_SZ (B_*64*ICH*192*2)
#define LT_OFF (PM_OFF + PM_SZ)
#define LT_SZ (B_*H_*512*1024)
#define ACC2_OFF (LT_OFF + LT_SZ)

__global__ __launch_bounds__(192) void kA(const float* __restrict__ s, const float* __restrict__ R,
                 const float* __restrict__ t, const float* __restrict__ Wq,
                 const float* __restrict__ Wk, const float* __restrict__ Wv,
                 const float* __restrict__ Wqp, const float* __restrict__ Wkp,
                 const float* __restrict__ Wvp, const float* __restrict__ gam,
                 float* __restrict__ ws) {
  int blk = blockIdx.x;
  int b = blk >> 10, i = blk & 1023;
  int tid = threadIdx.x;
  __shared__ float sl[16], rl[9], tl[3], part[96];
  if (tid < 16) sl[tid] = s[(b*I_ + i)*C_ + tid];
  else if (tid < 25) rl[tid-16] = R[(size_t)(b*I_+i)*9 + (tid-16)];
  else if (tid < 28) tl[tid-25] = t[(size_t)(b*I_+i)*3 + (tid-25)];
  __syncthreads();
  hf* QF  = (hf*)(ws + QF16_OFF) + (size_t)(b*I_+i)*392;
  hf* KF  = (hf*)(ws + KF16_OFF) + (size_t)(b*I_+i)*392;
  ushort* VPP = (ushort*)(ws + VPF_OFF);
  float* vv = ws + VV_OFF + (size_t)(b*I_+i)*192;
  {
    int hc = tid; int h = hc >> 4, c = hc & 15;
    float aq = 0.f, ak = 0.f, av = 0.f;
    #pragma unroll
    for (int ci = 0; ci < 16; ci++) {
      float sv = sl[ci];
      aq += sv * Wq[ci*192 + hc];
      ak += sv * Wk[ci*192 + hc];
      av += sv * Wv[ci*192 + hc];
    }
    const float s_qk = 0.25f * W_Lc * LOG2E;
    QF[h*32 + c] = (hf)(aq * s_qk);
    KF[h*32 + c] = (hf)ak;
    vv[hc] = av;
  }
  {
    float raw[3], px[3];
    if (tid < 96) {
      bool isq = tid < 48;
      int n = isq ? tid : tid - 48;
      const float* W = isq ? Wqp : Wkp;
      #pragma unroll
      for (int x = 0; x < 3; x++) {
        float a2 = 0.f;
        #pragma unroll
        for (int ci = 0; ci < 16; ci++) a2 += sl[ci] * W[ci*144 + n*3 + x];
        raw[x] = a2;
      }
      #pragma unroll
      for (int x = 0; x < 3; x++)
        px[x] = rl[x*3]*raw[0] + rl[x*3+1]*raw[1] + rl[x*3+2]*raw[2] + tl[x];
      int h = n >> 2, p = n & 3;
      part[tid] = px[0]*px[0] + px[1]*px[1] + px[2]*px[2];
      if (isq) {
        float g = gam[h];
        float sp = log1pf(expf(g));
        float coef2 = -0.5f * kW_C * sp * W_Lc * LOG2E;
        #pragma unroll
        for (int x = 0; x < 3; x++) QF[h*32 + 16 + p*3 + x] = (hf)(px[x] * (-2.0f * coef2));
      } else {
        #pragma unroll
        for (int x = 0; x < 3; x++) KF[h*32 + 16 + p*3 + x] = (hf)px[x];
      }
    } else {
      int n = tid - 96;
      #pragma unroll
      for (int x = 0; x < 3; x++) {
        float a2 = 0.f;
        #pragma unroll
        for (int ci = 0; ci < 16; ci++) a2 += sl[ci] * Wvp[ci*288 + n*3 + x];
        raw[x] = a2;
      }
      #pragma unroll
      for (int x = 0; x < 3; x++)
        px[x] = rl[x*3]*raw[0] + rl[x*3+1]*raw[1] + rl[x*3+2]*raw[2] + tl[x];
      int h = n >> 3, p = n & 7;
      size_t base = ((size_t)(b*512 + (i >> 1))*12 + h)*48 + (i & 1);
      #pragma unroll
      for (int x = 0; x < 3; x++) VPP[base + (p*3 + x)*2] = bc<ushort>((hf)px[x]);
    }
  }
  __syncthreads();
  if (tid < 24) {
    int h = tid % 12; bool isq = tid < 12;
    float g = gam[h];
    float sp = log1pf(expf(g));
    float coef2 = -0.5f * kW_C * sp * W_Lc * LOG2E;
    float s2 = 0.f;
    int base = isq ? h*4 : 48 + h*4;
    #pragma unroll
    for (int p = 0; p < 4; p++) s2 += part[base + p];
    if (isq) {
      QF[h*32 + 28] = (hf)(coef2 * s2);
      QF[h*32 + 29] = (hf)1.0f;
      QF[h*32 + 30] = (hf)0.0f;
      QF[h*32 + 31] = (hf)0.0f;
    } else {
      KF[h*32 + 28] = (hf)1.0f;
      KF[h*32 + 29] = (hf)(coef2 * s2);
      KF[h*32 + 30] = (hf)0.0f;
      KF[h*32 + 31] = (hf)0.0f;
    }
  }
}

// Pass 1 (MFMA, pipelined, LDS-slim): block = (b, jt of 64, ic of 16), 256 thr = 4 waves.
// 16 j x 64 i (4 tiles). QF A-frags direct from L2 (no qlds); z prefetched one tile
// ahead; lbias packed u32; in-reg LT pack (2x shfl_xor); 2 barriers/tile.
__global__ __launch_bounds__(256,6) void kB(const float* __restrict__ z,
                 const float* __restrict__ Wb, float* __restrict__ ws) {
  int blk = blockIdx.x;
  int ic = blk & (ICH-1); int jt = (blk >> 4) & 63; int b = blk >> 10;
  int tid = threadIdx.x;
  int w = tid >> 6, lane = tid & 63;
  int ln15 = lane & 15, l16 = lane >> 4;
  int j0 = jt*16;
  __shared__ u32 lqk[12*16*18];      // 13824 B  [h][j][i(16)+pad2] f32 bits
  __shared__ u32 lbias32[16*112];    // 7168 B   [i][h*9 + jp]
  const ushort* QFu = (const ushort*)(ws + QF16_OFF);
  const ushort* KFu = (const ushort*)(ws + KF16_OFF);
  hf8v kf[3];
  #pragma unroll
  for (int q = 0; q < 3; q++) {
    int h = w*3 + q;
    kf[q] = *(const hf8v*)&KFu[(size_t)(b*I_ + j0 + ln15)*392 + h*32 + l16*8];
  }
  hf4v wbf;
  #pragma unroll
  for (int e = 0; e < 4; e++) {
    int c = l16*4 + e;
    float v = (ln15 < 12) ? Wb[c*12 + ln15] * (W_Lc*LOG2E) : 0.f;
    wbf[e] = (hf)v;
  }
  u32* LTu_w = (u32*)(ws + LT_OFF);
  float m = -1e30f, S = 0.f;
  float4 zb0, zb1, zb2, zb3;
  {
    const float* zbase = z + ((size_t)(b*I_ + ic*64 + w*4)*I_ + j0 + ln15)*16 + l16*4;
    zb0 = *(const float4*)(zbase);
    zb1 = *(const float4*)(zbase + (size_t)I_*16);
    zb2 = *(const float4*)(zbase + (size_t)I_*32);
    zb3 = *(const float4*)(zbase + (size_t)I_*48);
  }
  for (int t = 0; t < 4; ++t) {
    int i0 = ic*64 + t*16;
    #pragma unroll
    for (int q = 0; q < 3; q++) {
      int h = w*3 + q;
      hf8v a = *(const hf8v*)&QFu[(size_t)(b*I_ + i0 + ln15)*392 + h*32 + l16*8];
      f32x4 c = {0.f, 0.f, 0.f, 0.f};
      c = __builtin_amdgcn_mfma_f32_16x16x32_f16(a, kf[q], c, 0, 0, 0);
      u32* dst = &lqk[(h*16 + ln15)*18 + l16*4];
      *(uint2*)dst     = make_uint2(bc<u32>(c[0]), bc<u32>(c[1]));
      *(uint2*)(dst+2) = make_uint2(bc<u32>(c[2]), bc<u32>(c[3]));
    }
    #pragma unroll
    for (int r = 0; r < 4; r++) {
      float4 zv = (r == 0) ? zb0 : (r == 1) ? zb1 : (r == 2) ? zb2 : zb3;
      int ii = w*4 + r;
      uint2 ap = make_uint2(pkrtz(zv.x, zv.y), pkrtz(zv.z, zv.w));
      hf4v a = bc<hf4v>(ap);
      f32x4 cb = {0.f, 0.f, 0.f, 0.f};
      cb = __builtin_amdgcn_mfma_f32_16x16x16f16(a, wbf, cb, 0, 0, 0);
      if (ln15 < 12) {
        u32 b01 = pkrtz(cb[0], cb[1]);
        u32 b23 = pkrtz(cb[2], cb[3]);
        *(uint2*)&lbias32[ii*112 + ln15*9 + l16*2] = make_uint2(b01, b23);
      }
    }
    if (t < 3) {
      const float* zbase = z + ((size_t)(b*I_ + ic*64 + (t+1)*16 + w*4)*I_ + j0 + ln15)*16 + l16*4;
      zb0 = *(const float4*)(zbase);
      zb1 = *(const float4*)(zbase + (size_t)I_*16);
      zb2 = *(const float4*)(zbase + (size_t)I_*32);
      zb3 = *(const float4*)(zbase + (size_t)I_*48);
    }
    __syncthreads();
    if (tid < 192) {
      int h = tid >> 4, jl = tid & 15;
      const u32* qk = &lqk[(h*16 + jl)*18];
      float l[16];
      #pragma unroll
      for (int i = 0; i < 16; i++) {
        u32 bb = lbias32[i*112 + h*9 + (jl >> 1)];
        ushort bu = (jl & 1) ? (ushort)(bb >> 16) : (ushort)(bb & 0xffffu);
        l[i] = bc<float>(qk[i]) + (float)bc<hf>(bu);
      }
      u32 lw[8];
      #pragma unroll
      for (int p = 0; p < 8; p++) lw[p] = pkrtz(l[2*p], l[2*p+1]);
      float lr[16];
      #pragma unroll
      for (int p = 0; p < 8; p++) { hf2 lh = bc<hf2>(lw[p]); lr[2*p] = (float)lh[0]; lr[2*p+1] = (float)lh[1]; }
      float m8[8];
      #pragma unroll
      for (int p = 0; p < 8; p++) m8[p] = fmaxf(lr[2*p], lr[2*p+1]);
      float mt = fmaxf(fmaxf(fmaxf(m8[0],m8[1]), fmaxf(m8[2],m8[3])),
                       fmaxf(fmaxf(m8[4],m8[5]), fmaxf(m8[6],m8[7])));
      float e[16];
      #pragma unroll
      for (int p = 0; p < 16; p++) e[p] = __builtin_amdgcn_exp2f(lr[p] - mt);
      float st = ((e[0]+e[1])+(e[2]+e[3])) + ((e[4]+e[5])+(e[6]+e[7]))
               + ((e[8]+e[9])+(e[10]+e[11])) + ((e[12]+e[13])+(e[14]+e[15]));
      float mn = fmaxf(m, mt);
      S = S * __builtin_amdgcn_exp2f(m - mn) + st * __builtin_amdgcn_exp2f(mt - mn);
      m = mn;
      u32 ex[8];
      #pragma unroll
      for (int p = 0; p < 8; p++) {
        u32 pw = (u32)__shfl_xor((int)lw[p], 1);
        ex[p] = (jl & 1) ? permhi(lw[p], pw) : permlo(pw, lw[p]);
      }
      u32 sw[8];
      #pragma unroll
      for (int p = 0; p < 8; p++) sw[p] = (u32)__shfl_xor((int)ex[p], 1);
      int par = jl & 1;
      u32 o0 = par ? sw[4] : ex[0];
      u32 o1 = par ? ex[4] : sw[0];
      u32 o2 = par ? sw[5] : ex[1];
      u32 o3 = par ? ex[5] : sw[1];
      u32 o4 = par ? sw[6] : ex[2];
      u32 o5 = par ? ex[6] : sw[2];
      u32 o6 = par ? sw[7] : ex[3];
      u32 o7 = par ? ex[7] : sw[3];
      u32* dst = LTu_w + ((size_t)(b*12+h)*512 + jt*8 + (jl>>1))*1024 + i0 + par*8;
      *(uint4*)dst     = make_uint4(o0, o1, o2, o3);
      *(uint4*)(dst+4) = make_uint4(o4, o5, o6, o7);
    }
    __syncthreads();
  }
  if (tid < 192) {
    float2* pm = (float2*)(ws + PM_OFF);
    pm[((size_t)(b*64+jt)*ICH + ic)*192 + tid] = make_float2(m, S);
  }
}

// merge ICH partial (m,S) -> SM[b][h][j] = (m, 1/S)
__global__ __launch_bounds__(192) void kB2(float* __restrict__ ws) {
  int blk = blockIdx.x; int jt = blk & 63, b = blk >> 6;
  int tid = threadIdx.x; int h = tid >> 4, jl = tid & 15;
  const float2* pm = (const float2*)(ws + PM_OFF) + (size_t)(b*64+jt)*ICH*192 + tid;
  float m = -1e30f, S = 0.f;
  #pragma unroll
  for (int ic = 0; ic < ICH; ic++) {
    float2 p = pm[ic*192];
    float mn = fmaxf(m, p.x);
    S = S * __builtin_amdgcn_exp2f(m - mn) + p.y * __builtin_amdgcn_exp2f(p.x - mn);
    m = mn;
  }
  int j = jt*16 + jl;
  float* sm = ws + SM_OFF + ((size_t)((b*12+h)*1024) + j)*2;
  sm[0] = m;
  sm[1] = 1.0f / S;
}

// Pass 2 (double-buffered): block = (b, it of 64, jc of jch). 16 i, stream j.
// LT/z staged via registers one tile ahead into alternate LDS buffer; 1 barrier/tile.
__global__ __launch_bounds__(192,3) void kC(const float* __restrict__ z,
                 float* __restrict__ ws, int jsh) {
  int blk = blockIdx.x;
  int jch = 1 << jsh;
  int jc = blk & (jch-1); int it = (blk >> jsh) & 63; int b = blk >> (jsh+6);
  int tid = threadIdx.x; int h = tid >> 4, il = tid & 15;
  int i = it*16 + il;
  __shared__ u32 llds[2][96*18];
  __shared__ u32 zplds[2][16*132];
  float opts[24], opair[16], rsum = 0.f;
  #pragma unroll
  for (int n = 0; n < 24; n++) opts[n] = 0.f;
  #pragma unroll
  for (int c = 0; c < 16; c++) opair[c] = 0.f;
  const u32* LTu = (const u32*)(ws + LT_OFF);
  const float* SM = ws + SM_OFF + (size_t)((b*12+h)*1024)*2;
  const ushort* VPP = (const ushort*)(ws + VPF_OFF);
  int chunk = I_ >> jsh;
  int nt = chunk >> 4;
  int hh = tid >> 4, rr = tid & 15, sjp = rr >> 1, sq = rr & 1;  // staging roles
  // z staging roles (3 slots of 192; slot2 valid for tid<128)
  int x0r = tid >> 5,        x0jp = (tid >> 2) & 7,        x0c = tid & 3;
  int x1r = (tid+192) >> 5,  x1jp = ((tid+192) >> 2) & 7,  x1c = (tid+192) & 3;
  int x2r = (tid+384) >> 5,  x2jp = ((tid+384) >> 2) & 7,  x2c = (tid+384) & 3;
  uint4 lta, ltb;
  float4 za0, zd0, za1, zd1, za2, zd2;
  // prologue: load + write tile 0 into buf 0
  {
    int j0 = jc*chunk;
    int jpg0 = j0 >> 1;
    const u32* src = LTu + ((size_t)(b*12+hh)*512 + jpg0 + sjp)*1024 + it*16 + sq*8;
    lta = *(const uint4*)src;
    ltb = *(const uint4*)(src + 4);
    const float* zb0p = z + ((size_t)(b*I_ + it*16 + x0r)*I_ + j0 + 2*x0jp)*16 + x0c*4;
    za0 = *(const float4*)zb0p; zd0 = *(const float4*)(zb0p + 16);
    const float* zb1p = z + ((size_t)(b*I_ + it*16 + x1r)*I_ + j0 + 2*x1jp)*16 + x1c*4;
    za1 = *(const float4*)zb1p; zd1 = *(const float4*)(zb1p + 16);
    if (tid < 128) {
      const float* zb2p = z + ((size_t)(b*I_ + it*16 + x2r)*I_ + j0 + 2*x2jp)*16 + x2c*4;
      za2 = *(const float4*)zb2p; zd2 = *(const float4*)(zb2p + 16);
    }
    u32* drow = llds[0] + (hh*8 + sjp)*18 + sq*8;
    *(uint2*)(drow + 0) = make_uint2(lta.x, lta.y);
    *(uint2*)(drow + 2) = make_uint2(lta.z, lta.w);
    *(uint2*)(drow + 4) = make_uint2(ltb.x, ltb.y);
    *(uint2*)(drow + 6) = make_uint2(ltb.z, ltb.w);
    *(uint4*)&zplds[0][x0r*132 + x0jp*16 + x0c*4] =
      make_uint4(pkrtz(za0.x, zd0.x), pkrtz(za0.y, zd0.y), pkrtz(za0.z, zd0.z), pkrtz(za0.w, zd0.w));
    *(uint4*)&zplds[0][x1r*132 + x1jp*16 + x1c*4] =
      make_uint4(pkrtz(za1.x, zd1.x), pkrtz(za1.y, zd1.y), pkrtz(za1.z, zd1.z), pkrtz(za1.w, zd1.w));
    if (tid < 128)
      *(uint4*)&zplds[0][x2r*132 + x2jp*16 + x2c*4] =
        make_uint4(pkrtz(za2.x, zd2.x), pkrtz(za2.y, zd2.y), pkrtz(za2.z, zd2.z), pkrtz(za2.w, zd2.w));
    __syncthreads();
  }
  for (int t = 0; t < nt; ++t) {
    int cur = t & 1;
    int j0 = jc*chunk + t*16;
    int jpg0 = j0 >> 1;
    // issue loads for tile t+1 (drain under compute)
    if (t + 1 < nt) {
      int j1 = j0 + 16;
      const u32* src = LTu + ((size_t)(b*12+hh)*512 + (j1>>1) + sjp)*1024 + it*16 + sq*8;
      lta = *(const uint4*)src;
      ltb = *(const uint4*)(src + 4);
      const float* zb0p = z + ((size_t)(b*I_ + it*16 + x0r)*I_ + j1 + 2*x0jp)*16 + x0c*4;
      za0 = *(const float4*)zb0p; zd0 = *(const float4*)(zb0p + 16);
      const float* zb1p = z + ((size_t)(b*I_ + it*16 + x1r)*I_ + j1 + 2*x1jp)*16 + x1c*4;
      za1 = *(const float4*)zb1p; zd1 = *(const float4*)(zb1p + 16);
      if (tid < 128) {
        const float* zb2p = z + ((size_t)(b*I_ + it*16 + x2r)*I_ + j1 + 2*x2jp)*16 + x2c*4;
        za2 = *(const float4*)zb2p; zd2 = *(const float4*)(zb2p + 16);
      }
    }
    #pragma unroll 2
    for (int jp = 0; jp < 8; ++jp) {
      u32 lp = llds[cur][(h*8 + jp)*18 + il];
      float4 st = *(const float4*)(SM + (size_t)(j0 + 2*jp)*2);
      const uint4* vp4 = (const uint4*)(VPP + ((size_t)(b*512 + jpg0 + jp)*12 + h)*48);
      uint4 va = vp4[0], vb = vp4[1], vc = vp4[2];
      uint4 vd = vp4[3], ve = vp4[4], vf = vp4[5];
      hf2 lh = bc<hf2>(lp);
      float w0 = __builtin_amdgcn_exp2f((float)lh[0] - st.x) * st.y;
      float w1 = __builtin_amdgcn_exp2f((float)lh[1] - st.z) * st.w;
      rsum += w0 + w1;
      u32 w2 = pkrtz(w0, w1);
      const u32* zr = &zplds[cur][il*132 + jp*16];
      uint4 p0 = *(const uint4*)(zr + 0), p1 = *(const uint4*)(zr + 4);
      uint4 p2 = *(const uint4*)(zr + 8), p3 = *(const uint4*)(zr + 12);
      opair[0]  = fdot2f(w2, p0.x, opair[0]);
      opair[1]  = fdot2f(w2, p0.y, opair[1]);
      opair[2]  = fdot2f(w2, p0.z, opair[2]);
      opair[3]  = fdot2f(w2, p0.w, opair[3]);
      opair[4]  = fdot2f(w2, p1.x, opair[4]);
      opair[5]  = fdot2f(w2, p1.y, opair[5]);
      opair[6]  = fdot2f(w2, p1.z, opair[6]);
      opair[7]  = fdot2f(w2, p1.w, opair[7]);
      opair[8]  = fdot2f(w2, p2.x, opair[8]);
      opair[9]  = fdot2f(w2, p2.y, opair[9]);
      opair[10] = fdot2f(w2, p2.z, opair[10]);
      opair[11] = fdot2f(w2, p2.w, opair[11]);
      opair[12] = fdot2f(w2, p3.x, opair[12]);
      opair[13] = fdot2f(w2, p3.y, opair[13]);
      opair[14] = fdot2f(w2, p3.z, opair[14]);
      opair[15] = fdot2f(w2, p3.w, opair[15]);
      opts[0]  = fdot2f(w2, va.x, opts[0]);
      opts[1]  = fdot2f(w2, va.y, opts[1]);
      opts[2]  = fdot2f(w2, va.z, opts[2]);
      opts[3]  = fdot2f(w2, va.w, opts[3]);
      opts[4]  = fdot2f(w2, vb.x, opts[4]);
      opts[5]  = fdot2f(w2, vb.y, opts[5]);
      opts[6]  = fdot2f(w2, vb.z, opts[6]);
      opts[7]  = fdot2f(w2, vb.w, opts[7]);
      opts[8]  = fdot2f(w2, vc.x, opts[8]);
      opts[9]  = fdot2f(w2, vc.y, opts[9]);
      opts[10] = fdot2f(w2, vc.z, opts[10]);
      opts[11] = fdot2f(w2, vc.w, opts[11]);
      opts[12] = fdot2f(w2, vd.x, opts[12]);
      opts[13] = fdot2f(w2, vd.y, opts[13]);
      opts[14] = fdot2f(w2, vd.z, opts[14]);
      opts[15] = fdot2f(w2, vd.w, opts[15]);
      opts[16] = fdot2f(w2, ve.x, opts[16]);
      opts[17] = fdot2f(w2, ve.y, opts[17]);
      opts[18] = fdot2f(w2, ve.z, opts[18]);
      opts[19] = fdot2f(w2, ve.w, opts[19]);
      opts[20] = fdot2f(w2, vf.x, opts[20]);
      opts[21] = fdot2f(w2, vf.y, opts[21]);
      opts[22] = fdot2f(w2, vf.z, opts[22]);
      opts[23] = fdot2f(w2, vf.w, opts[23]);
    }
    // write tile t+1 into the alternate buffer
    if (t + 1 < nt) {
      int nb = cur ^ 1;
      u32* drow = llds[nb] + (hh*8 + sjp)*18 + sq*8;
      *(uint2*)(drow + 0) = make_uint2(lta.x, lta.y);
      *(uint2*)(drow + 2) = make_uint2(lta.z, lta.w);
      *(uint2*)(drow + 4) = make_uint2(ltb.x, ltb.y);
      *(uint2*)(drow + 6) = make_uint2(ltb.z, ltb.w);
      *(uint4*)&zplds[nb][x0r*132 + x0jp*16 + x0c*4] =
        make_uint4(pkrtz(za0.x, zd0.x), pkrtz(za0.y, zd0.y), pkrtz(za0.z, zd0.z), pkrtz(za0.w, zd0.w));
      *(uint4*)&zplds[nb][x1r*132 + x1jp*16 + x1c*4] =
        make_uint4(pkrtz(za1.x, zd1.x), pkrtz(za1.y, zd1.y), pkrtz(za1.z, zd1.z), pkrtz(za1.w, zd1.w));
      if (tid < 128)
        *(uint4*)&zplds[nb][x2r*132 + x2jp*16 + x2c*4] =
          make_uint4(pkrtz(za2.x, zd2.x), pkrtz(za2.y, zd2.y), pkrtz(za2.z, zd2.z), pkrtz(za2.w, zd2.w));
      __syncthreads();
    }
  }
  ushort* ab = (ushort*)(ws + ACC2_OFF) + ((size_t)(b*I_+i)*jch + jc)*512;
  #pragma unroll
  for (int n = 0; n < 24; n++) ab[h*24 + n] = bc<ushort>((hf)opts[n]);
  #pragma unroll
  for (int c = 0; c < 16; c++) ab[288 + h*16 + c] = bc<ushort>((hf)opair[c]);
  ab[480 + h] = bc<ushort>((hf)rsum);
}

// Epilogue: reduce jch f16 partials, build cat[4][768], out = cat @ Wout + bout.
__global__ __launch_bounds__(256) void kD(const float* __restrict__ Wout, const float* __restrict__ bout,
                 const float* __restrict__ ws, float* __restrict__ out, int jsh) {
  int jch = 1 << jsh;
  int blk = blockIdx.x;
  int b = blk >> 8; int i0 = (blk & 255) << 2;
  int tid = threadIdx.x;
  __shared__ float accs[4*512];
  __shared__ float cat[4*776];
  __shared__ float red[256];
  const ushort* ACC2us = (const ushort*)(ws + ACC2_OFF);
  for (int idx = tid; idx < 4*512; idx += 256) {
    int r = idx >> 9, f = idx & 511;
    const ushort* src = ACC2us + (size_t)(b*I_+i0+r)*jch*512 + f;
    float ssum = 0.f;
    for (int jc = 0; jc < jch; jc++) ssum += (float)bc<hf>(src[jc*512]);
    accs[idx] = ssum;
  }
  __syncthreads();
  const float* vv = ws + VV_OFF;
  for (int idx = tid; idx < 4*768; idx += 256) {
    int r = idx / 768, f = idx - r*768;
    int i = i0 + r;
    const float* ab = accs + r*512;
    float val;
    if (f < 192) {
      int h = f >> 4, c = f & 15;
      val = vv[(size_t)(b*I_+i)*192 + h*16 + c] * ab[480 + h];
    } else if (f < 384) {
      val = ab[288 + (f - 192)];
    } else if (f < 672) {
      val = ab[f - 384];
    } else {
      int g = f - 672; int base = (g >> 3)*24 + (g & 7)*3;
      float x0 = ab[base], x1 = ab[base+1], x2 = ab[base+2];
      val = sqrtf(fmaxf(x0*x0 + x1*x1 + x2*x2, 1e-12f));
    }
    cat[r*776 + f] = val;
  }
  __syncthreads();
  {
    int r = tid >> 6, c = (tid >> 2) & 15, sseg = tid & 3;
    const float* cr = cat + r*776;
    float a = 0.f;
    for (int f = sseg*192; f < sseg*192 + 192; f++) a += cr[f] * Wout[f*16 + c];
    red[tid] = a;
  }
  __syncthreads();
  if ((tid & 3) == 0) {
    int r = tid >> 6, c = (tid >> 2) & 15;
    float sum = bout[c] + red[tid] + red[tid+1] + red[tid+2] + red[tid+3];
    out[((size_t)(b*I_) + i0 + r)*16 + c] = sum;
  }
}

extern "C" void kernel_launch(void* const* d_in, const int* in_sizes, int n_in,
                              void* d_out, int out_size, void* d_ws, size_t ws_size,
                              hipStream_t stream) {
  const float* s    = (const float*)d_in[0];
  const float* z    = (const float*)d_in[1];
  const float* R    = (const float*)d_in[2];
  const float* t    = (const float*)d_in[3];
  const float* Wq   = (const float*)d_in[4];
  const float* Wk   = (const float*)d_in[5];
  const float* Wv   = (const float*)d_in[6];
  const float* Wb   = (const float*)d_in[7];
  const float* Wqp  = (const float*)d_in[8];
  const float* Wkp  = (const float*)d_in[9];
  const float* Wvp  = (const float*)d_in[10];
  const float* gam  = (const float*)d_in[11];
  const float* Wout = (const float*)d_in[12];
  const float* bout = (const float*)d_in[13];
  float* out = (float*)d_out;
  float* ws = (float*)d_ws;

  // pick largest jch (power of 2, <=16) whose f16 partial buffer fits ws
  int jsh = 4;
  while (jsh > 0) {
    size_t need = ((size_t)ACC2_OFF + (size_t)B_*I_*(1u<<jsh)*256) * 4u;
    if (need <= ws_size) break;
    jsh--;
  }

  hipLaunchKernelGGL(kA, dim3(B_*I_), dim3(192), 0, stream,
                     s, R, t, Wq, Wk, Wv, Wqp, Wkp, Wvp, gam, ws);
  hipLaunchKernelGGL(kB, dim3(B_*64*ICH), dim3(256), 0, stream, z, Wb, ws);
  hipLaunchKernelGGL(kB2, dim3(B_*64), dim3(192), 0, stream, ws);
  hipLaunchKernelGGL(kC, dim3(B_*64*(1<<jsh)), dim3(192), 0, stream, z, ws, jsh);
  hipLaunchKernelGGL(kD, dim3(B_*256), dim3(256), 0, stream, Wout, bout, ws, out, jsh);
}

// Round 18
// 167.171 us; speedup vs baseline: 1.0798x; 1.0268x over previous
//
#include <hip/hip_runtime.h>
#include <hip/hip_bf16.h>
#include <math.h>

#define B_ 2
#define I_ 1024
#define C_ 16
#define H_ 12
#define ICH 16

__device__ __constant__ float kW_C = 0.23570226039551584f; // sqrt(2/(9*4))
#define W_Lc 0.5773502691896258f
#define LOG2E 1.4426950408889634f

typedef _Float16 hf;
typedef hf hf2 __attribute__((ext_vector_type(2)));
typedef hf hf4v __attribute__((ext_vector_type(4)));
typedef hf hf8v __attribute__((ext_vector_type(8)));
typedef float f32x4 __attribute__((ext_vector_type(4)));
typedef unsigned int u32;

template <typename T, typename F>
__device__ inline T bc(F f) { return __builtin_bit_cast(T, f); }

__device__ inline float fdot2f(u32 a, u32 b, float c) {
#if __has_builtin(__builtin_amdgcn_fdot2)
  return __builtin_amdgcn_fdot2(bc<hf2>(a), bc<hf2>(b), c, false);
#else
  hf2 x = bc<hf2>(a), y = bc<hf2>(b);
  return c + (float)x[0] * (float)y[0] + (float)x[1] * (float)y[1];
#endif
}

__device__ inline u32 pkrtz(float lo, float hi) {
#if __has_builtin(__builtin_amdgcn_cvt_pkrtz)
  return bc<u32>(__builtin_amdgcn_cvt_pkrtz(lo, hi));
#else
  hf2 t; t[0] = (hf)lo; t[1] = (hf)hi; return bc<u32>(t);
#endif
}

__device__ inline u32 permlo(u32 hiw, u32 low) { // (lo16=low.lo, hi16=hiw.lo)
#if __has_builtin(__builtin_amdgcn_perm)
  return __builtin_amdgcn_perm(hiw, low, 0x05040100u);
#else
  return (low & 0xffffu) | (hiw << 16);
#endif
}
__device__ inline u32 permhi(u32 hiw, u32 low) { // (lo16=low.hi, hi16=hiw.hi)
#if __has_builtin(__builtin_amdgcn_perm)
  return __builtin_amdgcn_perm(hiw, low, 0x07060302u);
#else
  return (low >> 16) | (hiw & 0xffff0000u);
#endif
}

// ws layout (float units):
// QF16 [B][I][392] hf   per-h 32 feats (q' | qp'' | cw*q2 | 1 | 0 0)
// KF16 [B][I][392] hf   per-h 32 feats (k | kp | 1 | cw*k2 | 0 0)
// VPP  [B][512 jp][12 h][48 us] paired vpts (ushort idx n*2+(j&1), n=p*3+x)
// VV   [B][I][192] f32
// SM   [B][12][1024][2] f32 (m, 1/S)
// pm   [B][64][ICH][192] float2
// LT   [B][12][512 jp][1024 i] u32 slots = (l_j0, l_j1) f16 pair
// acc2 [B][I][jch][512] f16 (opts 0:288, opair 288:480, rowsum 480:492)
#define QF16_OFF 0
#define QF16_SZ (B_*I_*196)
#define KF16_OFF (QF16_OFF + QF16_SZ)
#define KF16_SZ QF16_SZ
#define VPF_OFF (KF16_OFF + KF16_SZ)
#define VPF_SZ (B_*I_*144)
#define VV_OFF (VPF_OFF + VPF_SZ)
#define VV_SZ (B_*I_*192)
#define SM_OFF (VV_OFF + VV_SZ)
#define SM_SZ (B_*12*1024*2)
#define PM_OFF (SM_OFF + SM_SZ)
#define PM_SZ (B_*64*ICH*192*2)
#define LT_OFF (PM_OFF + PM_SZ)
#define LT_SZ (B_*H_*512*1024)
#define ACC2_OFF (LT_OFF + LT_SZ)

__global__ __launch_bounds__(192) void kA(const float* __restrict__ s, const float* __restrict__ R,
                 const float* __restrict__ t, const float* __restrict__ Wq,
                 const float* __restrict__ Wk, const float* __restrict__ Wv,
                 const float* __restrict__ Wqp, const float* __restrict__ Wkp,
                 const float* __restrict__ Wvp, const float* __restrict__ gam,
                 float* __restrict__ ws) {
  int blk = blockIdx.x;
  int b = blk >> 10, i = blk & 1023;
  int tid = threadIdx.x;
  __shared__ float sl[16], rl[9], tl[3], part[96];
  if (tid < 16) sl[tid] = s[(b*I_ + i)*C_ + tid];
  else if (tid < 25) rl[tid-16] = R[(size_t)(b*I_+i)*9 + (tid-16)];
  else if (tid < 28) tl[tid-25] = t[(size_t)(b*I_+i)*3 + (tid-25)];
  __syncthreads();
  hf* QF  = (hf*)(ws + QF16_OFF) + (size_t)(b*I_+i)*392;
  hf* KF  = (hf*)(ws + KF16_OFF) + (size_t)(b*I_+i)*392;
  ushort* VPP = (ushort*)(ws + VPF_OFF);
  float* vv = ws + VV_OFF + (size_t)(b*I_+i)*192;
  {
    int hc = tid; int h = hc >> 4, c = hc & 15;
    float aq = 0.f, ak = 0.f, av = 0.f;
    #pragma unroll
    for (int ci = 0; ci < 16; ci++) {
      float sv = sl[ci];
      aq += sv * Wq[ci*192 + hc];
      ak += sv * Wk[ci*192 + hc];
      av += sv * Wv[ci*192 + hc];
    }
    const float s_qk = 0.25f * W_Lc * LOG2E;
    QF[h*32 + c] = (hf)(aq * s_qk);
    KF[h*32 + c] = (hf)ak;
    vv[hc] = av;
  }
  {
    float raw[3], px[3];
    if (tid < 96) {
      bool isq = tid < 48;
      int n = isq ? tid : tid - 48;
      const float* W = isq ? Wqp : Wkp;
      #pragma unroll
      for (int x = 0; x < 3; x++) {
        float a2 = 0.f;
        #pragma unroll
        for (int ci = 0; ci < 16; ci++) a2 += sl[ci] * W[ci*144 + n*3 + x];
        raw[x] = a2;
      }
      #pragma unroll
      for (int x = 0; x < 3; x++)
        px[x] = rl[x*3]*raw[0] + rl[x*3+1]*raw[1] + rl[x*3+2]*raw[2] + tl[x];
      int h = n >> 2, p = n & 3;
      part[tid] = px[0]*px[0] + px[1]*px[1] + px[2]*px[2];
      if (isq) {
        float g = gam[h];
        float sp = log1pf(expf(g));
        float coef2 = -0.5f * kW_C * sp * W_Lc * LOG2E;
        #pragma unroll
        for (int x = 0; x < 3; x++) QF[h*32 + 16 + p*3 + x] = (hf)(px[x] * (-2.0f * coef2));
      } else {
        #pragma unroll
        for (int x = 0; x < 3; x++) KF[h*32 + 16 + p*3 + x] = (hf)px[x];
      }
    } else {
      int n = tid - 96;
      #pragma unroll
      for (int x = 0; x < 3; x++) {
        float a2 = 0.f;
        #pragma unroll
        for (int ci = 0; ci < 16; ci++) a2 += sl[ci] * Wvp[ci*288 + n*3 + x];
        raw[x] = a2;
      }
      #pragma unroll
      for (int x = 0; x < 3; x++)
        px[x] = rl[x*3]*raw[0] + rl[x*3+1]*raw[1] + rl[x*3+2]*raw[2] + tl[x];
      int h = n >> 3, p = n & 7;
      size_t base = ((size_t)(b*512 + (i >> 1))*12 + h)*48 + (i & 1);
      #pragma unroll
      for (int x = 0; x < 3; x++) VPP[base + (p*3 + x)*2] = bc<ushort>((hf)px[x]);
    }
  }
  __syncthreads();
  if (tid < 24) {
    int h = tid % 12; bool isq = tid < 12;
    float g = gam[h];
    float sp = log1pf(expf(g));
    float coef2 = -0.5f * kW_C * sp * W_Lc * LOG2E;
    float s2 = 0.f;
    int base = isq ? h*4 : 48 + h*4;
    #pragma unroll
    for (int p = 0; p < 4; p++) s2 += part[base + p];
    if (isq) {
      QF[h*32 + 28] = (hf)(coef2 * s2);
      QF[h*32 + 29] = (hf)1.0f;
      QF[h*32 + 30] = (hf)0.0f;
      QF[h*32 + 31] = (hf)0.0f;
    } else {
      KF[h*32 + 28] = (hf)1.0f;
      KF[h*32 + 29] = (hf)(coef2 * s2);
      KF[h*32 + 30] = (hf)0.0f;
      KF[h*32 + 31] = (hf)0.0f;
    }
  }
}

// Pass 1 (MFMA, pipelined, LDS-slim): block = (b, jt of 64, ic of 16), 256 thr = 4 waves.
// 16 j x 64 i (4 tiles). QF A-frags direct from L2 (no qlds); z prefetched one tile
// ahead; lbias packed u32; in-reg LT pack (2x shfl_xor); 2 barriers/tile.
// (256,4): VGPR cap 128, body uses ~55 -> NO spill ((256,6) forced 40 VGPR + 27MB spill).
__global__ __launch_bounds__(256,4) void kB(const float* __restrict__ z,
                 const float* __restrict__ Wb, float* __restrict__ ws) {
  int blk = blockIdx.x;
  int ic = blk & (ICH-1); int jt = (blk >> 4) & 63; int b = blk >> 10;
  int tid = threadIdx.x;
  int w = tid >> 6, lane = tid & 63;
  int ln15 = lane & 15, l16 = lane >> 4;
  int j0 = jt*16;
  __shared__ u32 lqk[12*16*18];      // 13824 B  [h][j][i(16)+pad2] f32 bits
  __shared__ u32 lbias32[16*112];    // 7168 B   [i][h*9 + jp]
  const ushort* QFu = (const ushort*)(ws + QF16_OFF);
  const ushort* KFu = (const ushort*)(ws + KF16_OFF);
  hf8v kf[3];
  #pragma unroll
  for (int q = 0; q < 3; q++) {
    int h = w*3 + q;
    kf[q] = *(const hf8v*)&KFu[(size_t)(b*I_ + j0 + ln15)*392 + h*32 + l16*8];
  }
  hf4v wbf;
  #pragma unroll
  for (int e = 0; e < 4; e++) {
    int c = l16*4 + e;
    float v = (ln15 < 12) ? Wb[c*12 + ln15] * (W_Lc*LOG2E) : 0.f;
    wbf[e] = (hf)v;
  }
  u32* LTu_w = (u32*)(ws + LT_OFF);
  float m = -1e30f, S = 0.f;
  float4 zb0, zb1, zb2, zb3;
  {
    const float* zbase = z + ((size_t)(b*I_ + ic*64 + w*4)*I_ + j0 + ln15)*16 + l16*4;
    zb0 = *(const float4*)(zbase);
    zb1 = *(const float4*)(zbase + (size_t)I_*16);
    zb2 = *(const float4*)(zbase + (size_t)I_*32);
    zb3 = *(const float4*)(zbase + (size_t)I_*48);
  }
  for (int t = 0; t < 4; ++t) {
    int i0 = ic*64 + t*16;
    #pragma unroll
    for (int q = 0; q < 3; q++) {
      int h = w*3 + q;
      hf8v a = *(const hf8v*)&QFu[(size_t)(b*I_ + i0 + ln15)*392 + h*32 + l16*8];
      f32x4 c = {0.f, 0.f, 0.f, 0.f};
      c = __builtin_amdgcn_mfma_f32_16x16x32_f16(a, kf[q], c, 0, 0, 0);
      u32* dst = &lqk[(h*16 + ln15)*18 + l16*4];
      *(uint2*)dst     = make_uint2(bc<u32>(c[0]), bc<u32>(c[1]));
      *(uint2*)(dst+2) = make_uint2(bc<u32>(c[2]), bc<u32>(c[3]));
    }
    #pragma unroll
    for (int r = 0; r < 4; r++) {
      float4 zv = (r == 0) ? zb0 : (r == 1) ? zb1 : (r == 2) ? zb2 : zb3;
      int ii = w*4 + r;
      uint2 ap = make_uint2(pkrtz(zv.x, zv.y), pkrtz(zv.z, zv.w));
      hf4v a = bc<hf4v>(ap);
      f32x4 cb = {0.f, 0.f, 0.f, 0.f};
      cb = __builtin_amdgcn_mfma_f32_16x16x16f16(a, wbf, cb, 0, 0, 0);
      if (ln15 < 12) {
        u32 b01 = pkrtz(cb[0], cb[1]);
        u32 b23 = pkrtz(cb[2], cb[3]);
        *(uint2*)&lbias32[ii*112 + ln15*9 + l16*2] = make_uint2(b01, b23);
      }
    }
    if (t < 3) {
      const float* zbase = z + ((size_t)(b*I_ + ic*64 + (t+1)*16 + w*4)*I_ + j0 + ln15)*16 + l16*4;
      zb0 = *(const float4*)(zbase);
      zb1 = *(const float4*)(zbase + (size_t)I_*16);
      zb2 = *(const float4*)(zbase + (size_t)I_*32);
      zb3 = *(const float4*)(zbase + (size_t)I_*48);
    }
    __syncthreads();
    if (tid < 192) {
      int h = tid >> 4, jl = tid & 15;
      const u32* qk = &lqk[(h*16 + jl)*18];
      float l[16];
      #pragma unroll
      for (int i = 0; i < 16; i++) {
        u32 bb = lbias32[i*112 + h*9 + (jl >> 1)];
        ushort bu = (jl & 1) ? (ushort)(bb >> 16) : (ushort)(bb & 0xffffu);
        l[i] = bc<float>(qk[i]) + (float)bc<hf>(bu);
      }
      u32 lw[8];
      #pragma unroll
      for (int p = 0; p < 8; p++) lw[p] = pkrtz(l[2*p], l[2*p+1]);
      float lr[16];
      #pragma unroll
      for (int p = 0; p < 8; p++) { hf2 lh = bc<hf2>(lw[p]); lr[2*p] = (float)lh[0]; lr[2*p+1] = (float)lh[1]; }
      float m8[8];
      #pragma unroll
      for (int p = 0; p < 8; p++) m8[p] = fmaxf(lr[2*p], lr[2*p+1]);
      float mt = fmaxf(fmaxf(fmaxf(m8[0],m8[1]), fmaxf(m8[2],m8[3])),
                       fmaxf(fmaxf(m8[4],m8[5]), fmaxf(m8[6],m8[7])));
      float e[16];
      #pragma unroll
      for (int p = 0; p < 16; p++) e[p] = __builtin_amdgcn_exp2f(lr[p] - mt);
      float st = ((e[0]+e[1])+(e[2]+e[3])) + ((e[4]+e[5])+(e[6]+e[7]))
               + ((e[8]+e[9])+(e[10]+e[11])) + ((e[12]+e[13])+(e[14]+e[15]));
      float mn = fmaxf(m, mt);
      S = S * __builtin_amdgcn_exp2f(m - mn) + st * __builtin_amdgcn_exp2f(mt - mn);
      m = mn;
      u32 ex[8];
      #pragma unroll
      for (int p = 0; p < 8; p++) {
        u32 pw = (u32)__shfl_xor((int)lw[p], 1);
        ex[p] = (jl & 1) ? permhi(lw[p], pw) : permlo(pw, lw[p]);
      }
      u32 sw[8];
      #pragma unroll
      for (int p = 0; p < 8; p++) sw[p] = (u32)__shfl_xor((int)ex[p], 1);
      int par = jl & 1;
      u32 o0 = par ? sw[4] : ex[0];
      u32 o1 = par ? ex[4] : sw[0];
      u32 o2 = par ? sw[5] : ex[1];
      u32 o3 = par ? ex[5] : sw[1];
      u32 o4 = par ? sw[6] : ex[2];
      u32 o5 = par ? ex[6] : sw[2];
      u32 o6 = par ? sw[7] : ex[3];
      u32 o7 = par ? ex[7] : sw[3];
      u32* dst = LTu_w + ((size_t)(b*12+h)*512 + jt*8 + (jl>>1))*1024 + i0 + par*8;
      *(uint4*)dst     = make_uint4(o0, o1, o2, o3);
      *(uint4*)(dst+4) = make_uint4(o4, o5, o6, o7);
    }
    __syncthreads();
  }
  if (tid < 192) {
    float2* pm = (float2*)(ws + PM_OFF);
    pm[((size_t)(b*64+jt)*ICH + ic)*192 + tid] = make_float2(m, S);
  }
}

// merge ICH partial (m,S) -> SM[b][h][j] = (m, 1/S)
__global__ __launch_bounds__(192) void kB2(float* __restrict__ ws) {
  int blk = blockIdx.x; int jt = blk & 63, b = blk >> 6;
  int tid = threadIdx.x; int h = tid >> 4, jl = tid & 15;
  const float2* pm = (const float2*)(ws + PM_OFF) + (size_t)(b*64+jt)*ICH*192 + tid;
  float m = -1e30f, S = 0.f;
  #pragma unroll
  for (int ic = 0; ic < ICH; ic++) {
    float2 p = pm[ic*192];
    float mn = fmaxf(m, p.x);
    S = S * __builtin_amdgcn_exp2f(m - mn) + p.y * __builtin_amdgcn_exp2f(p.x - mn);
    m = mn;
  }
  int j = jt*16 + jl;
  float* sm = ws + SM_OFF + ((size_t)((b*12+h)*1024) + j)*2;
  sm[0] = m;
  sm[1] = 1.0f / S;
}

// Pass 2 (double-buffered): block = (b, it of 64, jc of jch). 16 i, stream j.
// LT/z staged via registers one tile ahead into alternate LDS buffer; 1 barrier/tile.
__global__ __launch_bounds__(192,3) void kC(const float* __restrict__ z,
                 float* __restrict__ ws, int jsh) {
  int blk = blockIdx.x;
  int jch = 1 << jsh;
  int jc = blk & (jch-1); int it = (blk >> jsh) & 63; int b = blk >> (jsh+6);
  int tid = threadIdx.x; int h = tid >> 4, il = tid & 15;
  int i = it*16 + il;
  __shared__ u32 llds[2][96*18];
  __shared__ u32 zplds[2][16*132];
  float opts[24], opair[16], rsum = 0.f;
  #pragma unroll
  for (int n = 0; n < 24; n++) opts[n] = 0.f;
  #pragma unroll
  for (int c = 0; c < 16; c++) opair[c] = 0.f;
  const u32* LTu = (const u32*)(ws + LT_OFF);
  const float* SM = ws + SM_OFF + (size_t)((b*12+h)*1024)*2;
  const ushort* VPP = (const ushort*)(ws + VPF_OFF);
  int chunk = I_ >> jsh;
  int nt = chunk >> 4;
  int hh = tid >> 4, rr = tid & 15, sjp = rr >> 1, sq = rr & 1;  // staging roles
  int x0r = tid >> 5,        x0jp = (tid >> 2) & 7,        x0c = tid & 3;
  int x1r = (tid+192) >> 5,  x1jp = ((tid+192) >> 2) & 7,  x1c = (tid+192) & 3;
  int x2r = (tid+384) >> 5,  x2jp = ((tid+384) >> 2) & 7,  x2c = (tid+384) & 3;
  uint4 lta, ltb;
  float4 za0, zd0, za1, zd1, za2, zd2;
  {
    int j0 = jc*chunk;
    int jpg0 = j0 >> 1;
    const u32* src = LTu + ((size_t)(b*12+hh)*512 + jpg0 + sjp)*1024 + it*16 + sq*8;
    lta = *(const uint4*)src;
    ltb = *(const uint4*)(src + 4);
    const float* zb0p = z + ((size_t)(b*I_ + it*16 + x0r)*I_ + j0 + 2*x0jp)*16 + x0c*4;
    za0 = *(const float4*)zb0p; zd0 = *(const float4*)(zb0p + 16);
    const float* zb1p = z + ((size_t)(b*I_ + it*16 + x1r)*I_ + j0 + 2*x1jp)*16 + x1c*4;
    za1 = *(const float4*)zb1p; zd1 = *(const float4*)(zb1p + 16);
    if (tid < 128) {
      const float* zb2p = z + ((size_t)(b*I_ + it*16 + x2r)*I_ + j0 + 2*x2jp)*16 + x2c*4;
      za2 = *(const float4*)zb2p; zd2 = *(const float4*)(zb2p + 16);
    }
    u32* drow = llds[0] + (hh*8 + sjp)*18 + sq*8;
    *(uint2*)(drow + 0) = make_uint2(lta.x, lta.y);
    *(uint2*)(drow + 2) = make_uint2(lta.z, lta.w);
    *(uint2*)(drow + 4) = make_uint2(ltb.x, ltb.y);
    *(uint2*)(drow + 6) = make_uint2(ltb.z, ltb.w);
    *(uint4*)&zplds[0][x0r*132 + x0jp*16 + x0c*4] =
      make_uint4(pkrtz(za0.x, zd0.x), pkrtz(za0.y, zd0.y), pkrtz(za0.z, zd0.z), pkrtz(za0.w, zd0.w));
    *(uint4*)&zplds[0][x1r*132 + x1jp*16 + x1c*4] =
      make_uint4(pkrtz(za1.x, zd1.x), pkrtz(za1.y, zd1.y), pkrtz(za1.z, zd1.z), pkrtz(za1.w, zd1.w));
    if (tid < 128)
      *(uint4*)&zplds[0][x2r*132 + x2jp*16 + x2c*4] =
        make_uint4(pkrtz(za2.x, zd2.x), pkrtz(za2.y, zd2.y), pkrtz(za2.z, zd2.z), pkrtz(za2.w, zd2.w));
    __syncthreads();
  }
  for (int t = 0; t < nt; ++t) {
    int cur = t & 1;
    int j0 = jc*chunk + t*16;
    int jpg0 = j0 >> 1;
    if (t + 1 < nt) {
      int j1 = j0 + 16;
      const u32* src = LTu + ((size_t)(b*12+hh)*512 + (j1>>1) + sjp)*1024 + it*16 + sq*8;
      lta = *(const uint4*)src;
      ltb = *(const uint4*)(src + 4);
      const float* zb0p = z + ((size_t)(b*I_ + it*16 + x0r)*I_ + j1 + 2*x0jp)*16 + x0c*4;
      za0 = *(const float4*)zb0p; zd0 = *(const float4*)(zb0p + 16);
      const float* zb1p = z + ((size_t)(b*I_ + it*16 + x1r)*I_ + j1 + 2*x1jp)*16 + x1c*4;
      za1 = *(const float4*)zb1p; zd1 = *(const float4*)(zb1p + 16);
      if (tid < 128) {
        const float* zb2p = z + ((size_t)(b*I_ + it*16 + x2r)*I_ + j1 + 2*x2jp)*16 + x2c*4;
        za2 = *(const float4*)zb2p; zd2 = *(const float4*)(zb2p + 16);
      }
    }
    #pragma unroll 2
    for (int jp = 0; jp < 8; ++jp) {
      u32 lp = llds[cur][(h*8 + jp)*18 + il];
      float4 st = *(const float4*)(SM + (size_t)(j0 + 2*jp)*2);
      const uint4* vp4 = (const uint4*)(VPP + ((size_t)(b*512 + jpg0 + jp)*12 + h)*48);
      uint4 va = vp4[0], vb = vp4[1], vc = vp4[2];
      uint4 vd = vp4[3], ve = vp4[4], vf = vp4[5];
      hf2 lh = bc<hf2>(lp);
      float w0 = __builtin_amdgcn_exp2f((float)lh[0] - st.x) * st.y;
      float w1 = __builtin_amdgcn_exp2f((float)lh[1] - st.z) * st.w;
      rsum += w0 + w1;
      u32 w2 = pkrtz(w0, w1);
      const u32* zr = &zplds[cur][il*132 + jp*16];
      uint4 p0 = *(const uint4*)(zr + 0), p1 = *(const uint4*)(zr + 4);
      uint4 p2 = *(const uint4*)(zr + 8), p3 = *(const uint4*)(zr + 12);
      opair[0]  = fdot2f(w2, p0.x, opair[0]);
      opair[1]  = fdot2f(w2, p0.y, opair[1]);
      opair[2]  = fdot2f(w2, p0.z, opair[2]);
      opair[3]  = fdot2f(w2, p0.w, opair[3]);
      opair[4]  = fdot2f(w2, p1.x, opair[4]);
      opair[5]  = fdot2f(w2, p1.y, opair[5]);
      opair[6]  = fdot2f(w2, p1.z, opair[6]);
      opair[7]  = fdot2f(w2, p1.w, opair[7]);
      opair[8]  = fdot2f(w2, p2.x, opair[8]);
      opair[9]  = fdot2f(w2, p2.y, opair[9]);
      opair[10] = fdot2f(w2, p2.z, opair[10]);
      opair[11] = fdot2f(w2, p2.w, opair[11]);
      opair[12] = fdot2f(w2, p3.x, opair[12]);
      opair[13] = fdot2f(w2, p3.y, opair[13]);
      opair[14] = fdot2f(w2, p3.z, opair[14]);
      opair[15] = fdot2f(w2, p3.w, opair[15]);
      opts[0]  = fdot2f(w2, va.x, opts[0]);
      opts[1]  = fdot2f(w2, va.y, opts[1]);
      opts[2]  = fdot2f(w2, va.z, opts[2]);
      opts[3]  = fdot2f(w2, va.w, opts[3]);
      opts[4]  = fdot2f(w2, vb.x, opts[4]);
      opts[5]  = fdot2f(w2, vb.y, opts[5]);
      opts[6]  = fdot2f(w2, vb.z, opts[6]);
      opts[7]  = fdot2f(w2, vb.w, opts[7]);
      opts[8]  = fdot2f(w2, vc.x, opts[8]);
      opts[9]  = fdot2f(w2, vc.y, opts[9]);
      opts[10] = fdot2f(w2, vc.z, opts[10]);
      opts[11] = fdot2f(w2, vc.w, opts[11]);
      opts[12] = fdot2f(w2, vd.x, opts[12]);
      opts[13] = fdot2f(w2, vd.y, opts[13]);
      opts[14] = fdot2f(w2, vd.z, opts[14]);
      opts[15] = fdot2f(w2, vd.w, opts[15]);
      opts[16] = fdot2f(w2, ve.x, opts[16]);
      opts[17] = fdot2f(w2, ve.y, opts[17]);
      opts[18] = fdot2f(w2, ve.z, opts[18]);
      opts[19] = fdot2f(w2, ve.w, opts[19]);
      opts[20] = fdot2f(w2, vf.x, opts[20]);
      opts[21] = fdot2f(w2, vf.y, opts[21]);
      opts[22] = fdot2f(w2, vf.z, opts[22]);
      opts[23] = fdot2f(w2, vf.w, opts[23]);
    }
    if (t + 1 < nt) {
      int nb = cur ^ 1;
      u32* drow = llds[nb] + (hh*8 + sjp)*18 + sq*8;
      *(uint2*)(drow + 0) = make_uint2(lta.x, lta.y);
      *(uint2*)(drow + 2) = make_uint2(lta.z, lta.w);
      *(uint2*)(drow + 4) = make_uint2(ltb.x, ltb.y);
      *(uint2*)(drow + 6) = make_uint2(ltb.z, ltb.w);
      *(uint4*)&zplds[nb][x0r*132 + x0jp*16 + x0c*4] =
        make_uint4(pkrtz(za0.x, zd0.x), pkrtz(za0.y, zd0.y), pkrtz(za0.z, zd0.z), pkrtz(za0.w, zd0.w));
      *(uint4*)&zplds[nb][x1r*132 + x1jp*16 + x1c*4] =
        make_uint4(pkrtz(za1.x, zd1.x), pkrtz(za1.y, zd1.y), pkrtz(za1.z, zd1.z), pkrtz(za1.w, zd1.w));
      if (tid < 128)
        *(uint4*)&zplds[nb][x2r*132 + x2jp*16 + x2c*4] =
          make_uint4(pkrtz(za2.x, zd2.x), pkrtz(za2.y, zd2.y), pkrtz(za2.z, zd2.z), pkrtz(za2.w, zd2.w));
      __syncthreads();
    }
  }
  ushort* ab = (ushort*)(ws + ACC2_OFF) + ((size_t)(b*I_+i)*jch + jc)*512;
  #pragma unroll
  for (int n = 0; n < 24; n++) ab[h*24 + n] = bc<ushort>((hf)opts[n]);
  #pragma unroll
  for (int c = 0; c < 16; c++) ab[288 + h*16 + c] = bc<ushort>((hf)opair[c]);
  ab[480 + h] = bc<ushort>((hf)rsum);
}

// Epilogue: reduce jch f16 partials, build cat[4][768], out = cat @ Wout + bout.
__global__ __launch_bounds__(256) void kD(const float* __restrict__ Wout, const float* __restrict__ bout,
                 const float* __restrict__ ws, float* __restrict__ out, int jsh) {
  int jch = 1 << jsh;
  int blk = blockIdx.x;
  int b = blk >> 8; int i0 = (blk & 255) << 2;
  int tid = threadIdx.x;
  __shared__ float accs[4*512];
  __shared__ float cat[4*776];
  __shared__ float red[256];
  const ushort* ACC2us = (const ushort*)(ws + ACC2_OFF);
  for (int idx = tid; idx < 4*512; idx += 256) {
    int r = idx >> 9, f = idx & 511;
    const ushort* src = ACC2us + (size_t)(b*I_+i0+r)*jch*512 + f;
    float ssum = 0.f;
    for (int jc = 0; jc < jch; jc++) ssum += (float)bc<hf>(src[jc*512]);
    accs[idx] = ssum;
  }
  __syncthreads();
  const float* vv = ws + VV_OFF;
  for (int idx = tid; idx < 4*768; idx += 256) {
    int r = idx / 768, f = idx - r*768;
    int i = i0 + r;
    const float* ab = accs + r*512;
    float val;
    if (f < 192) {
      int h = f >> 4, c = f & 15;
      val = vv[(size_t)(b*I_+i)*192 + h*16 + c] * ab[480 + h];
    } else if (f < 384) {
      val = ab[288 + (f - 192)];
    } else if (f < 672) {
      val = ab[f - 384];
    } else {
      int g = f - 672; int base = (g >> 3)*24 + (g & 7)*3;
      float x0 = ab[base], x1 = ab[base+1], x2 = ab[base+2];
      val = sqrtf(fmaxf(x0*x0 + x1*x1 + x2*x2, 1e-12f));
    }
    cat[r*776 + f] = val;
  }
  __syncthreads();
  {
    int r = tid >> 6, c = (tid >> 2) & 15, sseg = tid & 3;
    const float* cr = cat + r*776;
    float a = 0.f;
    for (int f = sseg*192; f < sseg*192 + 192; f++) a += cr[f] * Wout[f*16 + c];
    red[tid] = a;
  }
  __syncthreads();
  if ((tid & 3) == 0) {
    int r = tid >> 6, c = (tid >> 2) & 15;
    float sum = bout[c] + red[tid] + red[tid+1] + red[tid+2] + red[tid+3];
    out[((size_t)(b*I_) + i0 + r)*16 + c] = sum;
  }
}

extern "C" void kernel_launch(void* const* d_in, const int* in_sizes, int n_in,
                              void* d_out, int out_size, void* d_ws, size_t ws_size,
                              hipStream_t stream) {
  const float* s    = (const float*)d_in[0];
  const float* z    = (const float*)d_in[1];
  const float* R    = (const float*)d_in[2];
  const float* t    = (const float*)d_in[3];
  const float* Wq   = (const float*)d_in[4];
  const float* Wk   = (const float*)d_in[5];
  const float* Wv   = (const float*)d_in[6];
  const float* Wb   = (const float*)d_in[7];
  const float* Wqp  = (const float*)d_in[8];
  const float* Wkp  = (const float*)d_in[9];
  const float* Wvp  = (const float*)d_in[10];
  const float* gam  = (const float*)d_in[11];
  const float* Wout = (const float*)d_in[12];
  const float* bout = (const float*)d_in[13];
  float* out = (float*)d_out;
  float* ws = (float*)d_ws;

  // pick largest jch (power of 2, <=16) whose f16 partial buffer fits ws
  int jsh = 4;
  while (jsh > 0) {
    size_t need = ((size_t)ACC2_OFF + (size_t)B_*I_*(1u<<jsh)*256) * 4u;
    if (need <= ws_size) break;
    jsh--;
  }

  hipLaunchKernelGGL(kA, dim3(B_*I_), dim3(192), 0, stream,
                     s, R, t, Wq, Wk, Wv, Wqp, Wkp, Wvp, gam, ws);
  hipLaunchKernelGGL(kB, dim3(B_*64*ICH), dim3(256), 0, stream, z, Wb, ws);
  hipLaunchKernelGGL(kB2, dim3(B_*64), dim3(192), 0, stream, ws);
  hipLaunchKernelGGL(kC, dim3(B_*64*(1<<jsh)), dim3(192), 0, stream, z, ws, jsh);
  hipLaunchKernelGGL(kD, dim3(B_*256), dim3(256), 0, stream, Wout, bout, ws, out, jsh);
}